// Round 4
// baseline (19473.125 us; speedup 1.0000x reference)
//
#include <hip/hip_runtime.h>
#include <cstdint>
#include <cstddef>
#include <cmath>

#define NLAYER 6
#define NH 12
#define DMODEL 384
#define DHEAD 32
#define DFFN 1536
#define BATCH 64
#define SEQ 512
#define NROWS (BATCH*SEQ)   // 32768
#define FFN_CHUNK 8192      // rows per FFN chunk (4 chunks)

// ---------------------------------------------------------------- utilities

__device__ inline float wave_reduce_sum(float v) {
    #pragma unroll
    for (int m = 32; m >= 1; m >>= 1) v += __shfl_xor(v, m, 64);
    return v;
}

__device__ inline float sigmoidf(float x) { return 1.0f / (1.0f + expf(-x)); }

__device__ inline float gelu_tanh(float x) {
    const float c = 0.7978845608028654f; // sqrt(2/pi)
    float t = tanhf(c * (x + 0.044715f * x * x * x));
    return 0.5f * x * (1.0f + t);
}

// ---------------------------------------------------------------- embedding + LN
__global__ __launch_bounds__(256)
void embed_ln_kernel(const int* __restrict__ ids, const float* __restrict__ we,
                     const float* __restrict__ pe, const float* __restrict__ te,
                     const float* __restrict__ g, const float* __restrict__ bb,
                     float* __restrict__ x)
{
    int row = blockIdx.x * 4 + (threadIdx.x >> 6);
    int lane = threadIdx.x & 63;
    int l = row & (SEQ - 1);
    int id = ids[row];
    float vals[6];
    float s = 0.f;
    #pragma unroll
    for (int t = 0; t < 6; ++t) {
        int d = lane + 64 * t;
        float v = we[(size_t)id * DMODEL + d] + pe[(size_t)l * DMODEL + d] + te[d];
        vals[t] = v; s += v;
    }
    s = wave_reduce_sum(s);
    float m = s * (1.0f / DMODEL);
    float s2 = 0.f;
    #pragma unroll
    for (int t = 0; t < 6; ++t) { float dd = vals[t] - m; s2 += dd * dd; }
    s2 = wave_reduce_sum(s2);
    float rs = rsqrtf(s2 * (1.0f / DMODEL) + 1e-12f);
    #pragma unroll
    for (int t = 0; t < 6; ++t) {
        int d = lane + 64 * t;
        x[(size_t)row * DMODEL + d] = (vals[t] - m) * rs * g[d] + bb[d];
    }
}

// ---------------------------------------------------------------- residual add + LN (in-place on x)
__global__ __launch_bounds__(256)
void add_ln_kernel(float* x, const float* __restrict__ r,
                   const float* __restrict__ g, const float* __restrict__ bb)
{
    int row = blockIdx.x * 4 + (threadIdx.x >> 6);
    int lane = threadIdx.x & 63;
    float vals[6];
    float s = 0.f;
    #pragma unroll
    for (int t = 0; t < 6; ++t) {
        int d = lane + 64 * t;
        size_t idx = (size_t)row * DMODEL + d;
        float v = x[idx] + r[idx];
        vals[t] = v; s += v;
    }
    s = wave_reduce_sum(s);
    float m = s * (1.0f / DMODEL);
    float s2 = 0.f;
    #pragma unroll
    for (int t = 0; t < 6; ++t) { float dd = vals[t] - m; s2 += dd * dd; }
    s2 = wave_reduce_sum(s2);
    float rs = rsqrtf(s2 * (1.0f / DMODEL) + 1e-12f);
    #pragma unroll
    for (int t = 0; t < 6; ++t) {
        int d = lane + 64 * t;
        x[(size_t)row * DMODEL + d] = (vals[t] - m) * rs * g[d] + bb[d];
    }
}

// ---------------------------------------------------------------- fp32 GEMM (as R0, verified-by-inspection)
__global__ __launch_bounds__(256, 2)
void gemm_bias(const float* __restrict__ A, const float* __restrict__ W,
               const float* __restrict__ bias, float* __restrict__ C,
               int M, int N, int K, int act)
{
    __shared__ float As[16][128];
    __shared__ float Ws[16][128];
    int tid = threadIdx.x;
    int row0 = blockIdx.x * 128, col0 = blockIdx.y * 128;
    int tx = tid & 15, ty = tid >> 4;
    float acc[2][2][4][4] = {};
    int am = tid >> 2, akq = tid & 3;
    int wk = tid >> 5, wn = tid & 31;

    for (int k0 = 0; k0 < K; k0 += 16) {
        float4 a0 = *(const float4*)(A + (size_t)(row0 + am) * K + k0 + akq * 4);
        float4 a1 = *(const float4*)(A + (size_t)(row0 + am + 64) * K + k0 + akq * 4);
        float4 w0 = *(const float4*)(W + (size_t)(k0 + wk) * N + col0 + wn * 4);
        float4 w1 = *(const float4*)(W + (size_t)(k0 + wk + 8) * N + col0 + wn * 4);
        __syncthreads();
        As[akq * 4 + 0][am] = a0.x; As[akq * 4 + 1][am] = a0.y;
        As[akq * 4 + 2][am] = a0.z; As[akq * 4 + 3][am] = a0.w;
        As[akq * 4 + 0][am + 64] = a1.x; As[akq * 4 + 1][am + 64] = a1.y;
        As[akq * 4 + 2][am + 64] = a1.z; As[akq * 4 + 3][am + 64] = a1.w;
        *(float4*)&Ws[wk][wn * 4] = w0;
        *(float4*)&Ws[wk + 8][wn * 4] = w1;
        __syncthreads();
        #pragma unroll
        for (int kk = 0; kk < 16; ++kk) {
            float4 aL = *(const float4*)&As[kk][ty * 4];
            float4 aH = *(const float4*)&As[kk][64 + ty * 4];
            float4 wL = *(const float4*)&Ws[kk][tx * 4];
            float4 wH = *(const float4*)&Ws[kk][64 + tx * 4];
            float a_[2][4] = {{aL.x, aL.y, aL.z, aL.w}, {aH.x, aH.y, aH.z, aH.w}};
            float w_[2][4] = {{wL.x, wL.y, wL.z, wL.w}, {wH.x, wH.y, wH.z, wH.w}};
            #pragma unroll
            for (int ii = 0; ii < 2; ++ii)
                #pragma unroll
                for (int jj = 0; jj < 2; ++jj)
                    #pragma unroll
                    for (int i = 0; i < 4; ++i)
                        #pragma unroll
                        for (int j = 0; j < 4; ++j)
                            acc[ii][jj][i][j] += a_[ii][i] * w_[jj][j];
        }
    }
    #pragma unroll
    for (int ii = 0; ii < 2; ++ii)
        #pragma unroll
        for (int i = 0; i < 4; ++i) {
            size_t row = row0 + ii * 64 + ty * 4 + i;
            #pragma unroll
            for (int jj = 0; jj < 2; ++jj) {
                int col = col0 + jj * 64 + tx * 4;
                float4 c;
                c.x = acc[ii][jj][i][0] + bias[col + 0];
                c.y = acc[ii][jj][i][1] + bias[col + 1];
                c.z = acc[ii][jj][i][2] + bias[col + 2];
                c.w = acc[ii][jj][i][3] + bias[col + 3];
                if (act == 1) {
                    c.x = gelu_tanh(gelu_tanh(c.x));
                    c.y = gelu_tanh(gelu_tanh(c.y));
                    c.z = gelu_tanh(gelu_tanh(c.z));
                    c.w = gelu_tanh(gelu_tanh(c.w));
                }
                *(float4*)&C[row * N + col] = c;
            }
        }
}

// ---------------------------------------------------------------- beta: SIMPLE — one thread per (row, head)
__global__ __launch_bounds__(256)
void beta_kernel(const float* __restrict__ x, const float* __restrict__ Wb,
                 const float* __restrict__ mask, float* __restrict__ beta)
{
    int t = blockIdx.x * 256 + threadIdx.x;      // 0 .. NROWS*NH-1
    int row = t / NH, h = t % NH;
    float s = 0.f;
    for (int d = 0; d < DMODEL; ++d)
        s += x[(size_t)row * DMODEL + d] * Wb[(size_t)d * NH + h];
    beta[t] = sigmoidf(s) * mask[row];
}

// ---------------------------------------------------------------- q/k l2norm: SIMPLE — one thread per head instance
__global__ __launch_bounds__(256)
void norm_qk_kernel(float* q, float* k, const float* __restrict__ mask)
{
    int t = blockIdx.x * 256 + threadIdx.x;      // 0 .. NROWS*NH-1
    int row = t / NH;
    float mk = mask[row];
    float* qp = q + (size_t)t * DHEAD;
    float* kp = k + (size_t)t * DHEAD;
    float qs = 0.f, ks = 0.f;
    #pragma unroll
    for (int j = 0; j < DHEAD; ++j) { qs += qp[j] * qp[j]; ks += kp[j] * kp[j]; }
    float qi = 1.0f / (sqrtf(qs) + 1e-6f);
    float ki = mk / (sqrtf(ks) + 1e-6f);
    #pragma unroll
    for (int j = 0; j < DHEAD; ++j) { qp[j] *= qi; kp[j] *= ki; }
}

// ---------------------------------------------------------------- delta-rule scan: SIMPLE
// Each lane owns one (bh, column n) pair with the FULL k-dimension state in
// registers — zero cross-lane communication. A 64-lane wave covers 2 bh's
// (half = lane>>5 selects which). 4 waves per block, LDS tiles are per-wave.
// o may alias v: o-writes for a tile happen after that tile's v is staged.
#define SCAN_T 16
__global__ __launch_bounds__(256)
void scan_kernel(const float* __restrict__ q, const float* __restrict__ k,
                 const float* __restrict__ v, const float* __restrict__ beta,
                 const float* __restrict__ dfast, const float* __restrict__ dslow,
                 float* __restrict__ o)
{
    __shared__ float qs[4][2][SCAN_T][32];
    __shared__ float ks[4][2][SCAN_T][32];
    __shared__ float vs[4][2][SCAN_T][32];
    __shared__ float bs[4][2][SCAN_T];

    int wv = threadIdx.x >> 6;                     // wave in block: 0..3
    int gw = blockIdx.x * 4 + wv;                  // global wave: 0..383
    int lane = threadIdx.x & 63;
    int half = lane >> 5, n = lane & 31;

    int bh0 = gw * 2, bh1 = gw * 2 + 1;
    int b0 = bh0 / NH, h0 = bh0 % NH;
    int b1 = bh1 / NH, h1 = bh1 % NH;
    int myb = half ? b1 : b0, myh = half ? h1 : h0;

    float gf = sigmoidf(dfast[myh]);
    float gs = sigmoidf(dslow[myh]);
    float Sf[DHEAD] = {}, Ss[DHEAD] = {};

    for (int t0 = 0; t0 < SEQ; t0 += SCAN_T) {
        __syncthreads();
        // stage q,k,v tiles for both bh's of this wave
        #pragma unroll
        for (int it = 0; it < (2 * SCAN_T * 32) / 64; ++it) {   // 16 iters
            int idx = lane + 64 * it;               // 0..1023
            int ib = idx >> 9;                      // 0..1
            int rr = (idx >> 5) & (SCAN_T - 1);     // 0..15
            int jj = idx & 31;
            int bb = ib ? b1 : b0, hh = ib ? h1 : h0;
            size_t gaddr = ((size_t)(bb * SEQ + t0 + rr) * NH + hh) * DHEAD + jj;
            qs[wv][ib][rr][jj] = q[gaddr];
            ks[wv][ib][rr][jj] = k[gaddr];
            vs[wv][ib][rr][jj] = v[gaddr];
        }
        if (lane < 2 * SCAN_T) {
            int ib = lane >> 4, rr = lane & (SCAN_T - 1);
            int bb = ib ? b1 : b0, hh = ib ? h1 : h0;
            bs[wv][ib][rr] = beta[(size_t)(bb * SEQ + t0 + rr) * NH + hh];
        }
        __syncthreads();

        for (int t = 0; t < SCAN_T; ++t) {
            float pf = 0.f, ps = 0.f;
            #pragma unroll
            for (int kk = 0; kk < DHEAD; ++kk) {
                float kv = ks[wv][half][t][kk];     // broadcast within half
                pf += kv * Sf[kk];
                ps += kv * Ss[kk];
            }
            float vt = vs[wv][half][t][n];
            float bt = bs[wv][half][t];
            float cf = bt * (vt - pf), cs = bt * (vt - ps);
            float ot = 0.f;
            #pragma unroll
            for (int kk = 0; kk < DHEAD; ++kk) {
                float kv = ks[wv][half][t][kk];
                float qv = qs[wv][half][t][kk];
                Sf[kk] = gf * Sf[kk] + kv * cf;
                Ss[kk] = gs * Ss[kk] + kv * cs;
                ot += qv * (Sf[kk] + Ss[kk]);
            }
            o[((size_t)(myb * SEQ + t0 + t) * NH + myh) * DHEAD + n] = 0.5f * ot;
        }
    }
}

// ---------------------------------------------------------------- masked mean-pool + l2 normalize
__global__ __launch_bounds__(384)
void pool_kernel(const float* __restrict__ x, const float* __restrict__ mask,
                 float* __restrict__ out)
{
    int b = blockIdx.x;
    int d = threadIdx.x;
    float acc = 0.f, msum = 0.f;
    for (int l = 0; l < SEQ; ++l) {
        float mk = mask[b * SEQ + l];
        acc += x[((size_t)b * SEQ + l) * DMODEL + d] * mk;
        msum += mk;
    }
    float emb = acc / fmaxf(msum, 1e-9f);
    __shared__ float red[6];
    float ss = wave_reduce_sum(emb * emb);
    int wvi = d >> 6, ln = d & 63;
    if (ln == 0) red[wvi] = ss;
    __syncthreads();
    float tot = 0.f;
    #pragma unroll
    for (int i = 0; i < 6; ++i) tot += red[i];
    float nrm = fmaxf(sqrtf(tot), 1e-12f);
    out[(size_t)b * DMODEL + d] = emb / nrm;
}

// ---------------------------------------------------------------- launch

extern "C" void kernel_launch(void* const* d_in, const int* in_sizes, int n_in,
                              void* d_out, int out_size, void* d_ws, size_t ws_size,
                              hipStream_t stream)
{
    const int*   ids   = (const int*)d_in[0];
    const float* mask  = (const float*)d_in[1];
    const float* we    = (const float*)d_in[2];
    const float* pe    = (const float*)d_in[3];
    const float* te    = (const float*)d_in[4];
    const float* elg   = (const float*)d_in[5];
    const float* elb   = (const float*)d_in[6];
    const float* Wq    = (const float*)d_in[7];
    const float* bq    = (const float*)d_in[8];
    const float* Wk    = (const float*)d_in[9];
    const float* bk    = (const float*)d_in[10];
    const float* Wv    = (const float*)d_in[11];
    const float* bv    = (const float*)d_in[12];
    const float* Wb    = (const float*)d_in[13];
    const float* dfast = (const float*)d_in[14];
    const float* dslow = (const float*)d_in[15];
    const float* Wo    = (const float*)d_in[16];
    const float* bo    = (const float*)d_in[17];
    const float* l1g   = (const float*)d_in[18];
    const float* l1b   = (const float*)d_in[19];
    const float* W1    = (const float*)d_in[20];
    const float* b1    = (const float*)d_in[21];
    const float* W2    = (const float*)d_in[22];
    const float* b2    = (const float*)d_in[23];
    const float* l2g   = (const float*)d_in[24];
    const float* l2b   = (const float*)d_in[25];
    float* out = (float*)d_out;

    // ---- fp32 workspace, 203 MB total ----
    const size_t RD = (size_t)NROWS * DMODEL;    // 12,582,912 elements
    float* x     = (float*)d_ws;                 // residual        (50.33 MB)
    float* betab = x + RD;                       // [NROWS,NH]      ( 1.57 MB)
    float* qslot = betab + (size_t)NROWS * NH;   // 50.33 MB
    float* kslot = qslot + RD;                   // 50.33 MB
    float* vslot = kslot + RD;                   // 50.33 MB
    // attention: q,k,v -> slots; o overwrites vslot; attn-out overwrites qslot
    // ffn (4 chunks of 8192 rows): h chunk -> kslot (8192*1536 fp32 = slot size),
    //                              W2 out  -> vslot

    dim3 blk256(256);
    dim3 rowsGrid(NROWS / 4);
    dim3 gemmGrid_D(NROWS / 128, DMODEL / 128);      // (256, 3)
    dim3 gemmGrid_C1(FFN_CHUNK / 128, DFFN / 128);   // (64, 12)
    dim3 gemmGrid_C2(FFN_CHUNK / 128, DMODEL / 128); // (64, 3)
    dim3 chunkRows(FFN_CHUNK / 4);
    dim3 headGrid(NROWS * NH / 256);                 // 1536 blocks
    dim3 scanGrid(BATCH * NH / 8);                   // 96 blocks, 4 waves, 2 bh/wave

    embed_ln_kernel<<<rowsGrid, blk256, 0, stream>>>(ids, we, pe, te, elg, elb, x);

    for (int i = 0; i < NLAYER; ++i) {
        const float* Wq_i = Wq + (size_t)i * DMODEL * DMODEL;
        const float* Wk_i = Wk + (size_t)i * DMODEL * DMODEL;
        const float* Wv_i = Wv + (size_t)i * DMODEL * DMODEL;
        const float* Wo_i = Wo + (size_t)i * DMODEL * DMODEL;
        const float* Wb_i = Wb + (size_t)i * DMODEL * NH;
        const float* W1_i = W1 + (size_t)i * DMODEL * DFFN;
        const float* W2_i = W2 + (size_t)i * DFFN * DMODEL;

        gemm_bias<<<gemmGrid_D, blk256, 0, stream>>>(x, Wq_i, bq + i * DMODEL, qslot,
                                                     NROWS, DMODEL, DMODEL, 0);
        gemm_bias<<<gemmGrid_D, blk256, 0, stream>>>(x, Wk_i, bk + i * DMODEL, kslot,
                                                     NROWS, DMODEL, DMODEL, 0);
        gemm_bias<<<gemmGrid_D, blk256, 0, stream>>>(x, Wv_i, bv + i * DMODEL, vslot,
                                                     NROWS, DMODEL, DMODEL, 0);
        beta_kernel<<<headGrid, blk256, 0, stream>>>(x, Wb_i, mask, betab);
        norm_qk_kernel<<<headGrid, blk256, 0, stream>>>(qslot, kslot, mask);
        scan_kernel<<<scanGrid, blk256, 0, stream>>>(qslot, kslot, vslot, betab,
                                                     dfast + i * NH, dslow + i * NH, vslot);
        gemm_bias<<<gemmGrid_D, blk256, 0, stream>>>(vslot, Wo_i, bo + i * DMODEL, qslot,
                                                     NROWS, DMODEL, DMODEL, 0);
        add_ln_kernel<<<rowsGrid, blk256, 0, stream>>>(x, qslot, l1g + i * DMODEL, l1b + i * DMODEL);

        for (int c = 0; c < NROWS / FFN_CHUNK; ++c) {
            const float* xc = x + (size_t)c * FFN_CHUNK * DMODEL;
            gemm_bias<<<gemmGrid_C1, blk256, 0, stream>>>(xc, W1_i, b1 + i * DFFN, kslot,
                                                          FFN_CHUNK, DFFN, DMODEL, 1);
            gemm_bias<<<gemmGrid_C2, blk256, 0, stream>>>(kslot, W2_i, b2 + i * DMODEL, vslot,
                                                          FFN_CHUNK, DMODEL, DFFN, 0);
            add_ln_kernel<<<chunkRows, blk256, 0, stream>>>(x + (size_t)c * FFN_CHUNK * DMODEL, vslot,
                                                            l2g + i * DMODEL, l2b + i * DMODEL);
        }
    }

    pool_kernel<<<dim3(BATCH), dim3(384), 0, stream>>>(x, mask, out);
}

// Round 5
// 6762.929 us; speedup vs baseline: 2.8794x; 2.8794x over previous
//
#include <hip/hip_runtime.h>
#include <cstdint>
#include <cstddef>
#include <cmath>

#define NLAYER 6
#define NH 12
#define DMODEL 384
#define DHEAD 32
#define DFFN 1536
#define BATCH 64
#define SEQ 512
#define NROWS (BATCH*SEQ)   // 32768
#define FFN_CHUNK 8192      // rows per FFN chunk (4 chunks)

typedef unsigned short ushort;
typedef __attribute__((ext_vector_type(8))) short bf16x8;   // 8 bf16 = 4 VGPRs
typedef __attribute__((ext_vector_type(4))) float f32x4;

// ---------------------------------------------------------------- utilities

__device__ inline float bf2f(ushort u) {
    union { unsigned int i; float f; } c; c.i = ((unsigned int)u) << 16; return c.f;
}
__device__ inline ushort f2bf(float f) {
    union { float f; unsigned int i; } c; c.f = f;
    unsigned int i = c.i;
    unsigned int lsb = (i >> 16) & 1u;
    i += 0x7fffu + lsb;          // round-to-nearest-even
    return (ushort)(i >> 16);
}

__device__ inline float ldf(const float* p) { return *p; }
__device__ inline float ldf(const ushort* p) { return bf2f(*p); }

__device__ inline float wave_reduce_sum(float v) {
    #pragma unroll
    for (int m = 32; m >= 1; m >>= 1) v += __shfl_xor(v, m, 64);
    return v;
}

__device__ inline float sigmoidf(float x) { return 1.0f / (1.0f + expf(-x)); }

__device__ inline float gelu_tanh(float x) {
    const float c = 0.7978845608028654f; // sqrt(2/pi)
    float t = tanhf(c * (x + 0.044715f * x * x * x));
    return 0.5f * x * (1.0f + t);
}

// load 16 elements as bf16 bit patterns
__device__ inline void loadcvt16(const float* p, ushort* d) {
    float4 f0 = *(const float4*)p,     f1 = *(const float4*)(p + 4);
    float4 f2 = *(const float4*)(p+8), f3 = *(const float4*)(p + 12);
    d[0]=f2bf(f0.x); d[1]=f2bf(f0.y); d[2]=f2bf(f0.z); d[3]=f2bf(f0.w);
    d[4]=f2bf(f1.x); d[5]=f2bf(f1.y); d[6]=f2bf(f1.z); d[7]=f2bf(f1.w);
    d[8]=f2bf(f2.x); d[9]=f2bf(f2.y); d[10]=f2bf(f2.z); d[11]=f2bf(f2.w);
    d[12]=f2bf(f3.x); d[13]=f2bf(f3.y); d[14]=f2bf(f3.z); d[15]=f2bf(f3.w);
}
__device__ inline void loadcvt16(const ushort* p, ushort* d) {
    ((uint4*)d)[0] = *(const uint4*)p;
    ((uint4*)d)[1] = *(const uint4*)(p + 8);
}

// ---------------------------------------------------------------- weight convert+transpose: W fp32 [L][K][N] -> WT bf16 [L][N][K]
__global__ __launch_bounds__(256)
void convT_kernel(const float* __restrict__ W, ushort* __restrict__ WT, int K, int N)
{
    __shared__ float t[32][33];
    int k0 = blockIdx.x * 32, n0 = blockIdx.y * 32, L = blockIdx.z;
    const float* Wl = W + (size_t)L * K * N;
    ushort* WTl = WT + (size_t)L * K * N;
    int tx = threadIdx.x & 31, ty = threadIdx.x >> 5;   // 32 x 8
    #pragma unroll
    for (int i = 0; i < 4; ++i)
        t[ty + 8 * i][tx] = Wl[(size_t)(k0 + ty + 8 * i) * N + n0 + tx];
    __syncthreads();
    #pragma unroll
    for (int i = 0; i < 4; ++i)
        WTl[(size_t)(n0 + ty + 8 * i) * K + k0 + tx] = f2bf(t[tx][ty + 8 * i]);
}

// ---------------------------------------------------------------- embedding + LN
__global__ __launch_bounds__(256)
void embed_ln_kernel(const int* __restrict__ ids, const float* __restrict__ we,
                     const float* __restrict__ pe, const float* __restrict__ te,
                     const float* __restrict__ g, const float* __restrict__ bb,
                     float* __restrict__ x)
{
    int row = blockIdx.x * 4 + (threadIdx.x >> 6);
    int lane = threadIdx.x & 63;
    int l = row & (SEQ - 1);
    int id = ids[row];
    float vals[6];
    float s = 0.f;
    #pragma unroll
    for (int t = 0; t < 6; ++t) {
        int d = lane + 64 * t;
        float v = we[(size_t)id * DMODEL + d] + pe[(size_t)l * DMODEL + d] + te[d];
        vals[t] = v; s += v;
    }
    s = wave_reduce_sum(s);
    float m = s * (1.0f / DMODEL);
    float s2 = 0.f;
    #pragma unroll
    for (int t = 0; t < 6; ++t) { float dd = vals[t] - m; s2 += dd * dd; }
    s2 = wave_reduce_sum(s2);
    float rs = rsqrtf(s2 * (1.0f / DMODEL) + 1e-12f);
    #pragma unroll
    for (int t = 0; t < 6; ++t) {
        int d = lane + 64 * t;
        x[(size_t)row * DMODEL + d] = (vals[t] - m) * rs * g[d] + bb[d];
    }
}

// ---------------------------------------------------------------- residual add + LN (in-place on x); r fp32 or bf16
template<typename TR>
__global__ __launch_bounds__(256)
void add_ln_kernel(float* x, const TR* __restrict__ r,
                   const float* __restrict__ g, const float* __restrict__ bb)
{
    int row = blockIdx.x * 4 + (threadIdx.x >> 6);
    int lane = threadIdx.x & 63;
    float vals[6];
    float s = 0.f;
    #pragma unroll
    for (int t = 0; t < 6; ++t) {
        int d = lane + 64 * t;
        size_t idx = (size_t)row * DMODEL + d;
        float v = x[idx] + ldf(r + idx);
        vals[t] = v; s += v;
    }
    s = wave_reduce_sum(s);
    float m = s * (1.0f / DMODEL);
    float s2 = 0.f;
    #pragma unroll
    for (int t = 0; t < 6; ++t) { float dd = vals[t] - m; s2 += dd * dd; }
    s2 = wave_reduce_sum(s2);
    float rs = rsqrtf(s2 * (1.0f / DMODEL) + 1e-12f);
    #pragma unroll
    for (int t = 0; t < 6; ++t) {
        int d = lane + 64 * t;
        x[(size_t)row * DMODEL + d] = (vals[t] - m) * rs * g[d] + bb[d];
    }
}

// ---------------------------------------------------------------- bf16 MFMA GEMM
// C[M,N] = A[M,K] @ W[K,N] + bias, W given pre-transposed bf16 WT[N][K].
// 128x128 tile, 256 threads = 4 waves in 2x2; each wave 64x64 via 4x4 MFMA
// tiles of 16x16x32. A fp32 (converted during staging) or bf16.
#define LDSTRIDE 40   // ushort elements per LDS row (32 + 8 pad, keeps 16B align)
template<typename TA, typename TC>
__global__ __launch_bounds__(256)
void gemm_mfma(const TA* __restrict__ A, const ushort* __restrict__ WT,
               const float* __restrict__ bias, TC* __restrict__ C,
               int M, int N, int K, int act)
{
    __shared__ __align__(16) ushort As[128 * LDSTRIDE];
    __shared__ __align__(16) ushort Bs[128 * LDSTRIDE];
    int tid = threadIdx.x;
    int lane = tid & 63, wv = tid >> 6;
    int waveM = wv >> 1, waveN = wv & 1;
    int lm = lane & 15, quad = lane >> 4;
    int row0 = blockIdx.x * 128, col0 = blockIdx.y * 128;
    int r2 = tid >> 1, kh = tid & 1;            // staging: row r2, k-halves of 16

    f32x4 acc[4][4] = {};

    for (int k0 = 0; k0 < K; k0 += 32) {
        __syncthreads();
        {
            ushort tmp[16];
            loadcvt16(A + (size_t)(row0 + r2) * K + k0 + kh * 16, tmp);
            *(uint4*)&As[r2 * LDSTRIDE + kh * 16]     = ((uint4*)tmp)[0];
            *(uint4*)&As[r2 * LDSTRIDE + kh * 16 + 8] = ((uint4*)tmp)[1];
            loadcvt16(WT + (size_t)(col0 + r2) * K + k0 + kh * 16, tmp);
            *(uint4*)&Bs[r2 * LDSTRIDE + kh * 16]     = ((uint4*)tmp)[0];
            *(uint4*)&Bs[r2 * LDSTRIDE + kh * 16 + 8] = ((uint4*)tmp)[1];
        }
        __syncthreads();

        bf16x8 af[4], bf[4];
        #pragma unroll
        for (int mt = 0; mt < 4; ++mt)
            af[mt] = *(const bf16x8*)&As[(waveM * 64 + mt * 16 + lm) * LDSTRIDE + quad * 8];
        #pragma unroll
        for (int nt = 0; nt < 4; ++nt)
            bf[nt] = *(const bf16x8*)&Bs[(waveN * 64 + nt * 16 + lm) * LDSTRIDE + quad * 8];
        #pragma unroll
        for (int mt = 0; mt < 4; ++mt)
            #pragma unroll
            for (int nt = 0; nt < 4; ++nt)
                acc[mt][nt] = __builtin_amdgcn_mfma_f32_16x16x32_bf16(af[mt], bf[nt], acc[mt][nt], 0, 0, 0);
    }

    // epilogue: row = quad*4 + reg, col = lane&15 within each 16x16 tile
    #pragma unroll
    for (int mt = 0; mt < 4; ++mt) {
        #pragma unroll
        for (int nt = 0; nt < 4; ++nt) {
            int col = col0 + waveN * 64 + nt * 16 + lm;
            float bv = bias[col];
            #pragma unroll
            for (int r = 0; r < 4; ++r) {
                int row = row0 + waveM * 64 + mt * 16 + quad * 4 + r;
                float val = acc[mt][nt][r] + bv;
                if (act == 1) val = gelu_tanh(gelu_tanh(val));
                if constexpr (sizeof(TC) == 2)
                    C[(size_t)row * N + col] = f2bf(val);
                else
                    C[(size_t)row * N + col] = val;
            }
        }
    }
}

// ---------------------------------------------------------------- beta: one thread per (row, head)  [verified R4]
__global__ __launch_bounds__(256)
void beta_kernel(const float* __restrict__ x, const float* __restrict__ Wb,
                 const float* __restrict__ mask, float* __restrict__ beta)
{
    int t = blockIdx.x * 256 + threadIdx.x;      // 0 .. NROWS*NH-1
    int row = t / NH, h = t % NH;
    float s = 0.f;
    for (int d = 0; d < DMODEL; ++d)
        s += x[(size_t)row * DMODEL + d] * Wb[(size_t)d * NH + h];
    beta[t] = sigmoidf(s) * mask[row];
}

// ---------------------------------------------------------------- q/k l2norm: 32 lanes per head instance, coalesced bf16
__global__ __launch_bounds__(256)
void norm_qk_kernel(ushort* q, ushort* k, const float* __restrict__ mask)
{
    int hid = blockIdx.x * 8 + (threadIdx.x >> 5);   // head instance 0..NROWS*NH-1
    int j = threadIdx.x & 31;
    int row = hid / NH;
    float mk = mask[row];
    size_t idx = (size_t)hid * DHEAD + j;

    float qv = bf2f(q[idx]);
    float ss = qv * qv;
    #pragma unroll
    for (int m = 1; m <= 16; m <<= 1) ss += __shfl_xor(ss, m, 32);
    q[idx] = f2bf(qv / (sqrtf(ss) + 1e-6f));

    float kv = bf2f(k[idx]);
    float ks = kv * kv;
    #pragma unroll
    for (int m = 1; m <= 16; m <<= 1) ks += __shfl_xor(ks, m, 32);
    k[idx] = f2bf((kv / (sqrtf(ks) + 1e-6f)) * mk);
}

// ---------------------------------------------------------------- delta-rule scan  [logic verified R4; bf16 IO; 1 wave/block]
// Each lane owns (bh, column n) with full k-state in registers; wave covers
// 2 bh via halves. o may alias v (tile staged before o-writes of that tile).
#define SCAN_T 16
__global__ __launch_bounds__(64)
void scan_kernel(const ushort* __restrict__ q, const ushort* __restrict__ k,
                 const ushort* __restrict__ v, const float* __restrict__ beta,
                 const float* __restrict__ dfast, const float* __restrict__ dslow,
                 ushort* __restrict__ o)
{
    __shared__ float qs[2][SCAN_T][32];
    __shared__ float ks[2][SCAN_T][32];
    __shared__ float vs[2][SCAN_T][32];
    __shared__ float bs[2][SCAN_T];

    int gw = blockIdx.x;
    int lane = threadIdx.x;
    int half = lane >> 5, n = lane & 31;

    int bh0 = gw * 2, bh1 = gw * 2 + 1;
    int b0 = bh0 / NH, h0 = bh0 % NH;
    int b1 = bh1 / NH, h1 = bh1 % NH;
    int myb = half ? b1 : b0, myh = half ? h1 : h0;

    float gf = sigmoidf(dfast[myh]);
    float gs = sigmoidf(dslow[myh]);
    float Sf[DHEAD] = {}, Ss[DHEAD] = {};

    for (int t0 = 0; t0 < SEQ; t0 += SCAN_T) {
        __syncthreads();
        #pragma unroll
        for (int it = 0; it < (2 * SCAN_T * 32) / 64; ++it) {   // 16 iters
            int idx = lane + 64 * it;               // 0..1023
            int ib = idx >> 9;                      // 0..1
            int rr = (idx >> 5) & (SCAN_T - 1);     // 0..15
            int jj = idx & 31;
            int bb = ib ? b1 : b0, hh = ib ? h1 : h0;
            size_t gaddr = ((size_t)(bb * SEQ + t0 + rr) * NH + hh) * DHEAD + jj;
            qs[ib][rr][jj] = bf2f(q[gaddr]);
            ks[ib][rr][jj] = bf2f(k[gaddr]);
            vs[ib][rr][jj] = bf2f(v[gaddr]);
        }
        if (lane < 2 * SCAN_T) {
            int ib = lane >> 4, rr = lane & (SCAN_T - 1);
            int bb = ib ? b1 : b0, hh = ib ? h1 : h0;
            bs[ib][rr] = beta[(size_t)(bb * SEQ + t0 + rr) * NH + hh];
        }
        __syncthreads();

        for (int t = 0; t < SCAN_T; ++t) {
            float pf = 0.f, ps = 0.f;
            #pragma unroll
            for (int kk = 0; kk < DHEAD; ++kk) {
                float kv = ks[half][t][kk];
                pf += kv * Sf[kk];
                ps += kv * Ss[kk];
            }
            float vt = vs[half][t][n];
            float bt = bs[half][t];
            float cf = bt * (vt - pf), cs = bt * (vt - ps);
            float ot = 0.f;
            #pragma unroll
            for (int kk = 0; kk < DHEAD; ++kk) {
                float kv = ks[half][t][kk];
                float qv = qs[half][t][kk];
                Sf[kk] = gf * Sf[kk] + kv * cf;
                Ss[kk] = gs * Ss[kk] + kv * cs;
                ot += qv * (Sf[kk] + Ss[kk]);
            }
            o[((size_t)(myb * SEQ + t0 + t) * NH + myh) * DHEAD + n] = f2bf(0.5f * ot);
        }
    }
}

// ---------------------------------------------------------------- masked mean-pool + l2 normalize
__global__ __launch_bounds__(384)
void pool_kernel(const float* __restrict__ x, const float* __restrict__ mask,
                 float* __restrict__ out)
{
    int b = blockIdx.x;
    int d = threadIdx.x;
    float acc = 0.f, msum = 0.f;
    for (int l = 0; l < SEQ; ++l) {
        float mk = mask[b * SEQ + l];
        acc += x[((size_t)b * SEQ + l) * DMODEL + d] * mk;
        msum += mk;
    }
    float emb = acc / fmaxf(msum, 1e-9f);
    __shared__ float red[6];
    float ss = wave_reduce_sum(emb * emb);
    int wvi = d >> 6, ln = d & 63;
    if (ln == 0) red[wvi] = ss;
    __syncthreads();
    float tot = 0.f;
    #pragma unroll
    for (int i = 0; i < 6; ++i) tot += red[i];
    float nrm = fmaxf(sqrtf(tot), 1e-12f);
    out[(size_t)b * DMODEL + d] = emb / nrm;
}

// ---------------------------------------------------------------- launch

extern "C" void kernel_launch(void* const* d_in, const int* in_sizes, int n_in,
                              void* d_out, int out_size, void* d_ws, size_t ws_size,
                              hipStream_t stream)
{
    const int*   ids   = (const int*)d_in[0];
    const float* mask  = (const float*)d_in[1];
    const float* we    = (const float*)d_in[2];
    const float* pe    = (const float*)d_in[3];
    const float* te    = (const float*)d_in[4];
    const float* elg   = (const float*)d_in[5];
    const float* elb   = (const float*)d_in[6];
    const float* Wq    = (const float*)d_in[7];
    const float* bq    = (const float*)d_in[8];
    const float* Wk    = (const float*)d_in[9];
    const float* bk    = (const float*)d_in[10];
    const float* Wv    = (const float*)d_in[11];
    const float* bv    = (const float*)d_in[12];
    const float* Wb    = (const float*)d_in[13];
    const float* dfast = (const float*)d_in[14];
    const float* dslow = (const float*)d_in[15];
    const float* Wo    = (const float*)d_in[16];
    const float* bo    = (const float*)d_in[17];
    const float* l1g   = (const float*)d_in[18];
    const float* l1b   = (const float*)d_in[19];
    const float* W1    = (const float*)d_in[20];
    const float* b1    = (const float*)d_in[21];
    const float* W2    = (const float*)d_in[22];
    const float* b2    = (const float*)d_in[23];
    const float* l2g   = (const float*)d_in[24];
    const float* l2b   = (const float*)d_in[25];
    float* out = (float*)d_out;

    // ---- workspace: 173.8 MB total (known-good ≤ 203 MB) ----
    const size_t RD = (size_t)NROWS * DMODEL;    // 12,582,912 elements
    float* x     = (float*)d_ws;                 // fp32 residual      (50.33 MB)
    float* betab = x + RD;                       // fp32 [NROWS,NH]    ( 1.57 MB)
    ushort* qb   = (ushort*)(betab + (size_t)NROWS * NH);  // bf16 (25.17 MB)
    ushort* kb   = qb + RD;                      // bf16; FFN-h chunk reuses (25.17)
    ushort* vb   = kb + RD;                      // bf16; o in-place   (25.17 MB)
    ushort* ab   = vb + RD;                      // bf16 branch out    (25.17 MB)
    ushort* WqT  = ab + RD;                      // transposed bf16 weights: 21.23 MB
    ushort* WkT  = WqT + (size_t)NLAYER * DMODEL * DMODEL;
    ushort* WvT  = WkT + (size_t)NLAYER * DMODEL * DMODEL;
    ushort* WoT  = WvT + (size_t)NLAYER * DMODEL * DMODEL;
    ushort* W1T  = WoT + (size_t)NLAYER * DMODEL * DMODEL;   // [1536][384]
    ushort* W2T  = W1T + (size_t)NLAYER * DMODEL * DFFN;     // [384][1536]

    dim3 blk256(256);
    dim3 rowsGrid(NROWS / 4);
    dim3 gemmGrid_D(NROWS / 128, DMODEL / 128);      // (256, 3)
    dim3 gemmGrid_C1(FFN_CHUNK / 128, DFFN / 128);   // (64, 12)
    dim3 gemmGrid_C2(FFN_CHUNK / 128, DMODEL / 128); // (64, 3)
    dim3 chunkRows(FFN_CHUNK / 4);
    dim3 headGrid(NROWS * NH / 256);                 // 1536 blocks (beta)
    dim3 normGrid(NROWS * NH / 8);                   // 49152 blocks
    dim3 scanGrid(BATCH * NH / 2);                   // 384 single-wave blocks

    // weight convert+transpose (runs every launch; deterministic)
    convT_kernel<<<dim3(12, 12, NLAYER), blk256, 0, stream>>>(Wq, WqT, DMODEL, DMODEL);
    convT_kernel<<<dim3(12, 12, NLAYER), blk256, 0, stream>>>(Wk, WkT, DMODEL, DMODEL);
    convT_kernel<<<dim3(12, 12, NLAYER), blk256, 0, stream>>>(Wv, WvT, DMODEL, DMODEL);
    convT_kernel<<<dim3(12, 12, NLAYER), blk256, 0, stream>>>(Wo, WoT, DMODEL, DMODEL);
    convT_kernel<<<dim3(12, 48, NLAYER), blk256, 0, stream>>>(W1, W1T, DMODEL, DFFN);
    convT_kernel<<<dim3(48, 12, NLAYER), blk256, 0, stream>>>(W2, W2T, DFFN, DMODEL);

    embed_ln_kernel<<<rowsGrid, blk256, 0, stream>>>(ids, we, pe, te, elg, elb, x);

    for (int i = 0; i < NLAYER; ++i) {
        const ushort* WqT_i = WqT + (size_t)i * DMODEL * DMODEL;
        const ushort* WkT_i = WkT + (size_t)i * DMODEL * DMODEL;
        const ushort* WvT_i = WvT + (size_t)i * DMODEL * DMODEL;
        const ushort* WoT_i = WoT + (size_t)i * DMODEL * DMODEL;
        const float*  Wb_i  = Wb  + (size_t)i * DMODEL * NH;
        const ushort* W1T_i = W1T + (size_t)i * DMODEL * DFFN;
        const ushort* W2T_i = W2T + (size_t)i * DFFN * DMODEL;

        gemm_mfma<float, ushort><<<gemmGrid_D, blk256, 0, stream>>>(x, WqT_i, bq + i * DMODEL, qb,
                                                                    NROWS, DMODEL, DMODEL, 0);
        gemm_mfma<float, ushort><<<gemmGrid_D, blk256, 0, stream>>>(x, WkT_i, bk + i * DMODEL, kb,
                                                                    NROWS, DMODEL, DMODEL, 0);
        gemm_mfma<float, ushort><<<gemmGrid_D, blk256, 0, stream>>>(x, WvT_i, bv + i * DMODEL, vb,
                                                                    NROWS, DMODEL, DMODEL, 0);
        beta_kernel<<<headGrid, blk256, 0, stream>>>(x, Wb_i, mask, betab);
        norm_qk_kernel<<<normGrid, blk256, 0, stream>>>(qb, kb, mask);
        scan_kernel<<<scanGrid, dim3(64), 0, stream>>>(qb, kb, vb, betab,
                                                       dfast + i * NH, dslow + i * NH, vb);
        gemm_mfma<ushort, ushort><<<gemmGrid_D, blk256, 0, stream>>>(vb, WoT_i, bo + i * DMODEL, ab,
                                                                     NROWS, DMODEL, DMODEL, 0);
        add_ln_kernel<ushort><<<rowsGrid, blk256, 0, stream>>>(x, ab, l1g + i * DMODEL, l1b + i * DMODEL);

        // FFN in 4 row-chunks: h chunk -> kb (dead), out chunk -> ab slice
        for (int c = 0; c < NROWS / FFN_CHUNK; ++c) {
            const float* xc = x + (size_t)c * FFN_CHUNK * DMODEL;
            ushort* abc = ab + (size_t)c * FFN_CHUNK * DMODEL;
            gemm_mfma<float, ushort><<<gemmGrid_C1, blk256, 0, stream>>>(xc, W1T_i, b1 + i * DFFN, kb,
                                                                         FFN_CHUNK, DFFN, DMODEL, 1);
            gemm_mfma<ushort, ushort><<<gemmGrid_C2, blk256, 0, stream>>>(kb, W2T_i, b2 + i * DMODEL, abc,
                                                                          FFN_CHUNK, DMODEL, DFFN, 0);
            add_ln_kernel<ushort><<<chunkRows, blk256, 0, stream>>>(x + (size_t)c * FFN_CHUNK * DMODEL, abc,
                                                                    l2g + i * DMODEL, l2b + i * DMODEL);
        }
    }

    pool_kernel<<<dim3(BATCH), dim3(384), 0, stream>>>(x, mask, out);
}

// Round 6
// 5038.191 us; speedup vs baseline: 3.8651x; 1.3423x over previous
//
#include <hip/hip_runtime.h>
#include <cstdint>
#include <cstddef>
#include <cmath>

#define NLAYER 6
#define NH 12
#define DMODEL 384
#define DHEAD 32
#define DFFN 1536
#define BATCH 64
#define SEQ 512
#define NROWS (BATCH*SEQ)   // 32768
#define FFN_CHUNK 8192      // rows per FFN chunk (4 chunks)

typedef unsigned short ushort;
typedef __attribute__((ext_vector_type(8))) short bf16x8;   // 8 bf16 = 4 VGPRs
typedef __attribute__((ext_vector_type(4))) float f32x4;

// ---------------------------------------------------------------- utilities

__device__ inline float bf2f(ushort u) {
    union { unsigned int i; float f; } c; c.i = ((unsigned int)u) << 16; return c.f;
}
__device__ inline ushort f2bf(float f) {
    union { float f; unsigned int i; } c; c.f = f;
    unsigned int i = c.i;
    unsigned int lsb = (i >> 16) & 1u;
    i += 0x7fffu + lsb;          // round-to-nearest-even
    return (ushort)(i >> 16);
}

__device__ inline float ldf(const float* p) { return *p; }
__device__ inline float ldf(const ushort* p) { return bf2f(*p); }

__device__ inline float wave_reduce_sum(float v) {
    #pragma unroll
    for (int m = 32; m >= 1; m >>= 1) v += __shfl_xor(v, m, 64);
    return v;
}

__device__ inline float sigmoidf(float x) { return 1.0f / (1.0f + expf(-x)); }

__device__ inline float gelu_tanh(float x) {
    const float c = 0.7978845608028654f; // sqrt(2/pi)
    float t = tanhf(c * (x + 0.044715f * x * x * x));
    return 0.5f * x * (1.0f + t);
}

// load 16 elements as bf16 bit patterns
__device__ inline void loadcvt16(const float* p, ushort* d) {
    float4 f0 = *(const float4*)p,     f1 = *(const float4*)(p + 4);
    float4 f2 = *(const float4*)(p+8), f3 = *(const float4*)(p + 12);
    d[0]=f2bf(f0.x); d[1]=f2bf(f0.y); d[2]=f2bf(f0.z); d[3]=f2bf(f0.w);
    d[4]=f2bf(f1.x); d[5]=f2bf(f1.y); d[6]=f2bf(f1.z); d[7]=f2bf(f1.w);
    d[8]=f2bf(f2.x); d[9]=f2bf(f2.y); d[10]=f2bf(f2.z); d[11]=f2bf(f2.w);
    d[12]=f2bf(f3.x); d[13]=f2bf(f3.y); d[14]=f2bf(f3.z); d[15]=f2bf(f3.w);
}
__device__ inline void loadcvt16(const ushort* p, ushort* d) {
    ((uint4*)d)[0] = *(const uint4*)p;
    ((uint4*)d)[1] = *(const uint4*)(p + 8);
}

// ---------------------------------------------------------------- weight convert+transpose: W fp32 [L][K][N] -> WT bf16 [L][N][K]
__global__ __launch_bounds__(256)
void convT_kernel(const float* __restrict__ W, ushort* __restrict__ WT, int K, int N)
{
    __shared__ float t[32][33];
    int k0 = blockIdx.x * 32, n0 = blockIdx.y * 32, L = blockIdx.z;
    const float* Wl = W + (size_t)L * K * N;
    ushort* WTl = WT + (size_t)L * K * N;
    int tx = threadIdx.x & 31, ty = threadIdx.x >> 5;   // 32 x 8
    #pragma unroll
    for (int i = 0; i < 4; ++i)
        t[ty + 8 * i][tx] = Wl[(size_t)(k0 + ty + 8 * i) * N + n0 + tx];
    __syncthreads();
    #pragma unroll
    for (int i = 0; i < 4; ++i)
        WTl[(size_t)(n0 + ty + 8 * i) * K + k0 + tx] = f2bf(t[tx][ty + 8 * i]);
}

// ---------------------------------------------------------------- embedding + LN
__global__ __launch_bounds__(256)
void embed_ln_kernel(const int* __restrict__ ids, const float* __restrict__ we,
                     const float* __restrict__ pe, const float* __restrict__ te,
                     const float* __restrict__ g, const float* __restrict__ bb,
                     float* __restrict__ x)
{
    int row = blockIdx.x * 4 + (threadIdx.x >> 6);
    int lane = threadIdx.x & 63;
    int l = row & (SEQ - 1);
    int id = ids[row];
    float vals[6];
    float s = 0.f;
    #pragma unroll
    for (int t = 0; t < 6; ++t) {
        int d = lane + 64 * t;
        float v = we[(size_t)id * DMODEL + d] + pe[(size_t)l * DMODEL + d] + te[d];
        vals[t] = v; s += v;
    }
    s = wave_reduce_sum(s);
    float m = s * (1.0f / DMODEL);
    float s2 = 0.f;
    #pragma unroll
    for (int t = 0; t < 6; ++t) { float dd = vals[t] - m; s2 += dd * dd; }
    s2 = wave_reduce_sum(s2);
    float rs = rsqrtf(s2 * (1.0f / DMODEL) + 1e-12f);
    #pragma unroll
    for (int t = 0; t < 6; ++t) {
        int d = lane + 64 * t;
        x[(size_t)row * DMODEL + d] = (vals[t] - m) * rs * g[d] + bb[d];
    }
}

// ---------------------------------------------------------------- residual add + LN (in-place on x); r fp32 or bf16
template<typename TR>
__global__ __launch_bounds__(256)
void add_ln_kernel(float* x, const TR* __restrict__ r,
                   const float* __restrict__ g, const float* __restrict__ bb)
{
    int row = blockIdx.x * 4 + (threadIdx.x >> 6);
    int lane = threadIdx.x & 63;
    float vals[6];
    float s = 0.f;
    #pragma unroll
    for (int t = 0; t < 6; ++t) {
        int d = lane + 64 * t;
        size_t idx = (size_t)row * DMODEL + d;
        float v = x[idx] + ldf(r + idx);
        vals[t] = v; s += v;
    }
    s = wave_reduce_sum(s);
    float m = s * (1.0f / DMODEL);
    float s2 = 0.f;
    #pragma unroll
    for (int t = 0; t < 6; ++t) { float dd = vals[t] - m; s2 += dd * dd; }
    s2 = wave_reduce_sum(s2);
    float rs = rsqrtf(s2 * (1.0f / DMODEL) + 1e-12f);
    #pragma unroll
    for (int t = 0; t < 6; ++t) {
        int d = lane + 64 * t;
        x[(size_t)row * DMODEL + d] = (vals[t] - m) * rs * g[d] + bb[d];
    }
}

// ---------------------------------------------------------------- bf16 MFMA GEMM  [verified R5]
#define LDSTRIDE 40   // ushort elements per LDS row (32 + 8 pad, keeps 16B align)
template<typename TA, typename TC>
__global__ __launch_bounds__(256)
void gemm_mfma(const TA* __restrict__ A, const ushort* __restrict__ WT,
               const float* __restrict__ bias, TC* __restrict__ C,
               int M, int N, int K, int act)
{
    __shared__ __align__(16) ushort As[128 * LDSTRIDE];
    __shared__ __align__(16) ushort Bs[128 * LDSTRIDE];
    int tid = threadIdx.x;
    int lane = tid & 63, wv = tid >> 6;
    int waveM = wv >> 1, waveN = wv & 1;
    int lm = lane & 15, quad = lane >> 4;
    int row0 = blockIdx.x * 128, col0 = blockIdx.y * 128;
    int r2 = tid >> 1, kh = tid & 1;            // staging: row r2, k-halves of 16

    f32x4 acc[4][4] = {};

    for (int k0 = 0; k0 < K; k0 += 32) {
        __syncthreads();
        {
            ushort tmp[16];
            loadcvt16(A + (size_t)(row0 + r2) * K + k0 + kh * 16, tmp);
            *(uint4*)&As[r2 * LDSTRIDE + kh * 16]     = ((uint4*)tmp)[0];
            *(uint4*)&As[r2 * LDSTRIDE + kh * 16 + 8] = ((uint4*)tmp)[1];
            loadcvt16(WT + (size_t)(col0 + r2) * K + k0 + kh * 16, tmp);
            *(uint4*)&Bs[r2 * LDSTRIDE + kh * 16]     = ((uint4*)tmp)[0];
            *(uint4*)&Bs[r2 * LDSTRIDE + kh * 16 + 8] = ((uint4*)tmp)[1];
        }
        __syncthreads();

        bf16x8 af[4], bf[4];
        #pragma unroll
        for (int mt = 0; mt < 4; ++mt)
            af[mt] = *(const bf16x8*)&As[(waveM * 64 + mt * 16 + lm) * LDSTRIDE + quad * 8];
        #pragma unroll
        for (int nt = 0; nt < 4; ++nt)
            bf[nt] = *(const bf16x8*)&Bs[(waveN * 64 + nt * 16 + lm) * LDSTRIDE + quad * 8];
        #pragma unroll
        for (int mt = 0; mt < 4; ++mt)
            #pragma unroll
            for (int nt = 0; nt < 4; ++nt)
                acc[mt][nt] = __builtin_amdgcn_mfma_f32_16x16x32_bf16(af[mt], bf[nt], acc[mt][nt], 0, 0, 0);
    }

    #pragma unroll
    for (int mt = 0; mt < 4; ++mt) {
        #pragma unroll
        for (int nt = 0; nt < 4; ++nt) {
            int col = col0 + waveN * 64 + nt * 16 + lm;
            float bv = bias[col];
            #pragma unroll
            for (int r = 0; r < 4; ++r) {
                int row = row0 + waveM * 64 + mt * 16 + quad * 4 + r;
                float val = acc[mt][nt][r] + bv;
                if (act == 1) val = gelu_tanh(gelu_tanh(val));
                if constexpr (sizeof(TC) == 2)
                    C[(size_t)row * N + col] = f2bf(val);
                else
                    C[(size_t)row * N + col] = val;
            }
        }
    }
}

// ---------------------------------------------------------------- beta: one thread per (row, head)  [verified R4]
__global__ __launch_bounds__(256)
void beta_kernel(const float* __restrict__ x, const float* __restrict__ Wb,
                 const float* __restrict__ mask, float* __restrict__ beta)
{
    int t = blockIdx.x * 256 + threadIdx.x;      // 0 .. NROWS*NH-1
    int row = t / NH, h = t % NH;
    float s = 0.f;
    for (int d = 0; d < DMODEL; ++d)
        s += x[(size_t)row * DMODEL + d] * Wb[(size_t)d * NH + h];
    beta[t] = sigmoidf(s) * mask[row];
}

// ---------------------------------------------------------------- q/k l2norm: 32 lanes per head instance, coalesced bf16 [verified R5]
__global__ __launch_bounds__(256)
void norm_qk_kernel(ushort* q, ushort* k, const float* __restrict__ mask)
{
    int hid = blockIdx.x * 8 + (threadIdx.x >> 5);   // head instance 0..NROWS*NH-1
    int j = threadIdx.x & 31;
    int row = hid / NH;
    float mk = mask[row];
    size_t idx = (size_t)hid * DHEAD + j;

    float qv = bf2f(q[idx]);
    float ss = qv * qv;
    #pragma unroll
    for (int m = 1; m <= 16; m <<= 1) ss += __shfl_xor(ss, m, 32);
    q[idx] = f2bf(qv / (sqrtf(ss) + 1e-6f));

    float kv = bf2f(k[idx]);
    float ks = kv * kv;
    #pragma unroll
    for (int m = 1; m <= 16; m <<= 1) ks += __shfl_xor(ks, m, 32);
    k[idx] = f2bf((kv / (sqrtf(ks) + 1e-6f)) * mk);
}

// ---------------------------------------------------------------- delta-rule scan, v3
// One wave per (b,h). lane = (half = k-half, n = column). State Sf/Ss[16]
// per lane covers k in [half*16, half*16+16) for column n. Cross-half
// reduction via one shfl_xor(.,32). Manual tree reductions keep the
// critical path at ~log2 depth. LDS tiles fp32, 36-float padded rows,
// compute reads are b128 broadcasts. o may alias v (tile staged first).
#define SCAN_T 32
#define SROW 36
__global__ __launch_bounds__(64)
void scan_kernel(const ushort* __restrict__ q, const ushort* __restrict__ k,
                 const ushort* __restrict__ v, const float* __restrict__ beta,
                 const float* __restrict__ dfast, const float* __restrict__ dslow,
                 ushort* __restrict__ o)
{
    __shared__ float qs[SCAN_T][SROW];
    __shared__ float ks[SCAN_T][SROW];
    __shared__ float vs[SCAN_T][SROW];
    __shared__ float bs[SCAN_T];

    int bh = blockIdx.x;
    int b = bh / NH, h = bh % NH;
    int lane = threadIdx.x;
    int half = lane >> 5, n = lane & 31, kb0 = half * 16;

    float gf = sigmoidf(dfast[h]);
    float gs = sigmoidf(dslow[h]);
    float Sf[16] = {}, Ss[16] = {};

    int srow = lane >> 2, sseg = lane & 3;       // staging: 16 rows x 4 segs of 8

    for (int t0 = 0; t0 < SEQ; t0 += SCAN_T) {
        __syncthreads();
        #pragma unroll
        for (int it = 0; it < 2; ++it) {
            int rr = srow + 16 * it;
            size_t gaddr = ((size_t)(b * SEQ + t0 + rr) * NH + h) * DHEAD + sseg * 8;
            uint4 uq = *(const uint4*)(q + gaddr);
            uint4 uk = *(const uint4*)(k + gaddr);
            uint4 uv = *(const uint4*)(v + gaddr);
            ushort tq[8], tk[8], tv[8];
            *(uint4*)tq = uq; *(uint4*)tk = uk; *(uint4*)tv = uv;
            #pragma unroll
            for (int j = 0; j < 8; ++j) {
                qs[rr][sseg * 8 + j] = bf2f(tq[j]);
                ks[rr][sseg * 8 + j] = bf2f(tk[j]);
                vs[rr][sseg * 8 + j] = bf2f(tv[j]);
            }
        }
        if (lane < SCAN_T)
            bs[lane] = beta[(size_t)(b * SEQ + t0 + lane) * NH + h];
        __syncthreads();

        for (int t = 0; t < SCAN_T; ++t) {
            float kt[16], qt[16];
            *(float4*)&kt[0]  = *(const float4*)&ks[t][kb0 + 0];
            *(float4*)&kt[4]  = *(const float4*)&ks[t][kb0 + 4];
            *(float4*)&kt[8]  = *(const float4*)&ks[t][kb0 + 8];
            *(float4*)&kt[12] = *(const float4*)&ks[t][kb0 + 12];
            *(float4*)&qt[0]  = *(const float4*)&qs[t][kb0 + 0];
            *(float4*)&qt[4]  = *(const float4*)&qs[t][kb0 + 4];
            *(float4*)&qt[8]  = *(const float4*)&qs[t][kb0 + 8];
            *(float4*)&qt[12] = *(const float4*)&qs[t][kb0 + 12];
            float vt = vs[t][n], bt = bs[t];

            float pf[16], ps[16];
            #pragma unroll
            for (int j = 0; j < 16; ++j) { pf[j] = kt[j] * Sf[j]; ps[j] = kt[j] * Ss[j]; }
            #pragma unroll
            for (int off = 8; off >= 1; off >>= 1)
                #pragma unroll
                for (int j = 0; j < off; ++j) { pf[j] += pf[j + off]; ps[j] += ps[j + off]; }
            float pft = pf[0] + __shfl_xor(pf[0], 32, 64);
            float pst = ps[0] + __shfl_xor(ps[0], 32, 64);

            float cf = bt * (vt - pft), cs = bt * (vt - pst);
            float ot[16];
            #pragma unroll
            for (int j = 0; j < 16; ++j) {
                Sf[j] = gf * Sf[j] + kt[j] * cf;
                Ss[j] = gs * Ss[j] + kt[j] * cs;
                ot[j] = qt[j] * (Sf[j] + Ss[j]);
            }
            #pragma unroll
            for (int off = 8; off >= 1; off >>= 1)
                #pragma unroll
                for (int j = 0; j < off; ++j) ot[j] += ot[j + off];
            float ott = ot[0] + __shfl_xor(ot[0], 32, 64);
            if (half == 0)
                o[((size_t)(b * SEQ + t0 + t) * NH + h) * DHEAD + n] = f2bf(0.5f * ott);
        }
    }
}

// ---------------------------------------------------------------- masked mean-pool + l2 normalize
__global__ __launch_bounds__(384)
void pool_kernel(const float* __restrict__ x, const float* __restrict__ mask,
                 float* __restrict__ out)
{
    int b = blockIdx.x;
    int d = threadIdx.x;
    float acc = 0.f, msum = 0.f;
    for (int l = 0; l < SEQ; ++l) {
        float mk = mask[b * SEQ + l];
        acc += x[((size_t)b * SEQ + l) * DMODEL + d] * mk;
        msum += mk;
    }
    float emb = acc / fmaxf(msum, 1e-9f);
    __shared__ float red[6];
    float ss = wave_reduce_sum(emb * emb);
    int wvi = d >> 6, ln = d & 63;
    if (ln == 0) red[wvi] = ss;
    __syncthreads();
    float tot = 0.f;
    #pragma unroll
    for (int i = 0; i < 6; ++i) tot += red[i];
    float nrm = fmaxf(sqrtf(tot), 1e-12f);
    out[(size_t)b * DMODEL + d] = emb / nrm;
}

// ---------------------------------------------------------------- launch

extern "C" void kernel_launch(void* const* d_in, const int* in_sizes, int n_in,
                              void* d_out, int out_size, void* d_ws, size_t ws_size,
                              hipStream_t stream)
{
    const int*   ids   = (const int*)d_in[0];
    const float* mask  = (const float*)d_in[1];
    const float* we    = (const float*)d_in[2];
    const float* pe    = (const float*)d_in[3];
    const float* te    = (const float*)d_in[4];
    const float* elg   = (const float*)d_in[5];
    const float* elb   = (const float*)d_in[6];
    const float* Wq    = (const float*)d_in[7];
    const float* bq    = (const float*)d_in[8];
    const float* Wk    = (const float*)d_in[9];
    const float* bk    = (const float*)d_in[10];
    const float* Wv    = (const float*)d_in[11];
    const float* bv    = (const float*)d_in[12];
    const float* Wb    = (const float*)d_in[13];
    const float* dfast = (const float*)d_in[14];
    const float* dslow = (const float*)d_in[15];
    const float* Wo    = (const float*)d_in[16];
    const float* bo    = (const float*)d_in[17];
    const float* l1g   = (const float*)d_in[18];
    const float* l1b   = (const float*)d_in[19];
    const float* W1    = (const float*)d_in[20];
    const float* b1    = (const float*)d_in[21];
    const float* W2    = (const float*)d_in[22];
    const float* b2    = (const float*)d_in[23];
    const float* l2g   = (const float*)d_in[24];
    const float* l2b   = (const float*)d_in[25];
    float* out = (float*)d_out;

    // ---- workspace: 173.8 MB total (known-good ≤ 203 MB) ----
    const size_t RD = (size_t)NROWS * DMODEL;    // 12,582,912 elements
    float* x     = (float*)d_ws;                 // fp32 residual      (50.33 MB)
    float* betab = x + RD;                       // fp32 [NROWS,NH]    ( 1.57 MB)
    ushort* qb   = (ushort*)(betab + (size_t)NROWS * NH);  // bf16 (25.17 MB)
    ushort* kb   = qb + RD;                      // bf16; FFN-h chunk reuses (25.17)
    ushort* vb   = kb + RD;                      // bf16; o in-place   (25.17 MB)
    ushort* ab   = vb + RD;                      // bf16 branch out    (25.17 MB)
    ushort* WqT  = ab + RD;                      // transposed bf16 weights: 21.23 MB
    ushort* WkT  = WqT + (size_t)NLAYER * DMODEL * DMODEL;
    ushort* WvT  = WkT + (size_t)NLAYER * DMODEL * DMODEL;
    ushort* WoT  = WvT + (size_t)NLAYER * DMODEL * DMODEL;
    ushort* W1T  = WoT + (size_t)NLAYER * DMODEL * DMODEL;   // [1536][384]
    ushort* W2T  = W1T + (size_t)NLAYER * DMODEL * DFFN;     // [384][1536]

    dim3 blk256(256);
    dim3 rowsGrid(NROWS / 4);
    dim3 gemmGrid_D(NROWS / 128, DMODEL / 128);      // (256, 3)
    dim3 gemmGrid_C1(FFN_CHUNK / 128, DFFN / 128);   // (64, 12)
    dim3 gemmGrid_C2(FFN_CHUNK / 128, DMODEL / 128); // (64, 3)
    dim3 chunkRows(FFN_CHUNK / 4);
    dim3 headGrid(NROWS * NH / 256);                 // 1536 blocks (beta)
    dim3 normGrid(NROWS * NH / 8);                   // 49152 blocks
    dim3 scanGrid(BATCH * NH);                       // 768 single-wave blocks

    convT_kernel<<<dim3(12, 12, NLAYER), blk256, 0, stream>>>(Wq, WqT, DMODEL, DMODEL);
    convT_kernel<<<dim3(12, 12, NLAYER), blk256, 0, stream>>>(Wk, WkT, DMODEL, DMODEL);
    convT_kernel<<<dim3(12, 12, NLAYER), blk256, 0, stream>>>(Wv, WvT, DMODEL, DMODEL);
    convT_kernel<<<dim3(12, 12, NLAYER), blk256, 0, stream>>>(Wo, WoT, DMODEL, DMODEL);
    convT_kernel<<<dim3(12, 48, NLAYER), blk256, 0, stream>>>(W1, W1T, DMODEL, DFFN);
    convT_kernel<<<dim3(48, 12, NLAYER), blk256, 0, stream>>>(W2, W2T, DFFN, DMODEL);

    embed_ln_kernel<<<rowsGrid, blk256, 0, stream>>>(ids, we, pe, te, elg, elb, x);

    for (int i = 0; i < NLAYER; ++i) {
        const ushort* WqT_i = WqT + (size_t)i * DMODEL * DMODEL;
        const ushort* WkT_i = WkT + (size_t)i * DMODEL * DMODEL;
        const ushort* WvT_i = WvT + (size_t)i * DMODEL * DMODEL;
        const ushort* WoT_i = WoT + (size_t)i * DMODEL * DMODEL;
        const float*  Wb_i  = Wb  + (size_t)i * DMODEL * NH;
        const ushort* W1T_i = W1T + (size_t)i * DMODEL * DFFN;
        const ushort* W2T_i = W2T + (size_t)i * DFFN * DMODEL;

        gemm_mfma<float, ushort><<<gemmGrid_D, blk256, 0, stream>>>(x, WqT_i, bq + i * DMODEL, qb,
                                                                    NROWS, DMODEL, DMODEL, 0);
        gemm_mfma<float, ushort><<<gemmGrid_D, blk256, 0, stream>>>(x, WkT_i, bk + i * DMODEL, kb,
                                                                    NROWS, DMODEL, DMODEL, 0);
        gemm_mfma<float, ushort><<<gemmGrid_D, blk256, 0, stream>>>(x, WvT_i, bv + i * DMODEL, vb,
                                                                    NROWS, DMODEL, DMODEL, 0);
        beta_kernel<<<headGrid, blk256, 0, stream>>>(x, Wb_i, mask, betab);
        norm_qk_kernel<<<normGrid, blk256, 0, stream>>>(qb, kb, mask);
        scan_kernel<<<scanGrid, dim3(64), 0, stream>>>(qb, kb, vb, betab,
                                                       dfast + i * NH, dslow + i * NH, vb);
        gemm_mfma<ushort, ushort><<<gemmGrid_D, blk256, 0, stream>>>(vb, WoT_i, bo + i * DMODEL, ab,
                                                                     NROWS, DMODEL, DMODEL, 0);
        add_ln_kernel<ushort><<<rowsGrid, blk256, 0, stream>>>(x, ab, l1g + i * DMODEL, l1b + i * DMODEL);

        for (int c = 0; c < NROWS / FFN_CHUNK; ++c) {
            const float* xc = x + (size_t)c * FFN_CHUNK * DMODEL;
            ushort* abc = ab + (size_t)c * FFN_CHUNK * DMODEL;
            gemm_mfma<float, ushort><<<gemmGrid_C1, blk256, 0, stream>>>(xc, W1T_i, b1 + i * DFFN, kb,
                                                                         FFN_CHUNK, DFFN, DMODEL, 1);
            gemm_mfma<ushort, ushort><<<gemmGrid_C2, blk256, 0, stream>>>(kb, W2T_i, b2 + i * DMODEL, abc,
                                                                          FFN_CHUNK, DMODEL, DFFN, 0);
            add_ln_kernel<ushort><<<chunkRows, blk256, 0, stream>>>(x + (size_t)c * FFN_CHUNK * DMODEL, abc,
                                                                    l2g + i * DMODEL, l2b + i * DMODEL);
        }
    }

    pool_kernel<<<dim3(BATCH), dim3(384), 0, stream>>>(x, mask, out);
}

// Round 7
// 4398.266 us; speedup vs baseline: 4.4275x; 1.1455x over previous
//
#include <hip/hip_runtime.h>
#include <cstdint>
#include <cstddef>
#include <cmath>

#define NLAYER 6
#define NH 12
#define DMODEL 384
#define DHEAD 32
#define DFFN 1536
#define BATCH 64
#define SEQ 512
#define NROWS (BATCH*SEQ)   // 32768
#define FFN_CHUNK 8192      // rows per FFN chunk (4 chunks)

typedef unsigned short ushort;
typedef __attribute__((ext_vector_type(8))) short bf16x8;   // 8 bf16 = 4 VGPRs
typedef __attribute__((ext_vector_type(4))) float f32x4;

// ---------------------------------------------------------------- utilities

__device__ inline float bf2f(ushort u) {
    union { unsigned int i; float f; } c; c.i = ((unsigned int)u) << 16; return c.f;
}
__device__ inline ushort f2bf(float f) {
    union { float f; unsigned int i; } c; c.f = f;
    unsigned int i = c.i;
    unsigned int lsb = (i >> 16) & 1u;
    i += 0x7fffu + lsb;          // round-to-nearest-even
    return (ushort)(i >> 16);
}

__device__ inline float wave_reduce_sum(float v) {
    #pragma unroll
    for (int m = 32; m >= 1; m >>= 1) v += __shfl_xor(v, m, 64);
    return v;
}

__device__ inline float sigmoidf(float x) { return 1.0f / (1.0f + expf(-x)); }

__device__ inline float gelu_tanh(float x) {
    const float c = 0.7978845608028654f; // sqrt(2/pi)
    float t = tanhf(c * (x + 0.044715f * x * x * x));
    return 0.5f * x * (1.0f + t);
}

// async global->LDS, 16 bytes per lane; lds base must be wave-uniform
__device__ inline void async16(const ushort* g, ushort* l) {
    __builtin_amdgcn_global_load_lds(
        (const __attribute__((address_space(1))) unsigned int*)g,
        (__attribute__((address_space(3))) unsigned int*)l,
        16, 0, 0);
}

// ---------------------------------------------------------------- weight convert+transpose: W fp32 [L][K][N] -> WT bf16 [L][N][K]
__global__ __launch_bounds__(256)
void convT_kernel(const float* __restrict__ W, ushort* __restrict__ WT, int K, int N)
{
    __shared__ float t[32][33];
    int k0 = blockIdx.x * 32, n0 = blockIdx.y * 32, L = blockIdx.z;
    const float* Wl = W + (size_t)L * K * N;
    ushort* WTl = WT + (size_t)L * K * N;
    int tx = threadIdx.x & 31, ty = threadIdx.x >> 5;   // 32 x 8
    #pragma unroll
    for (int i = 0; i < 4; ++i)
        t[ty + 8 * i][tx] = Wl[(size_t)(k0 + ty + 8 * i) * N + n0 + tx];
    __syncthreads();
    #pragma unroll
    for (int i = 0; i < 4; ++i)
        WTl[(size_t)(n0 + ty + 8 * i) * K + k0 + tx] = f2bf(t[tx][ty + 8 * i]);
}

// ---------------------------------------------------------------- embedding + LN (writes fp32 x and bf16 xb)
__global__ __launch_bounds__(256)
void embed_ln_kernel(const int* __restrict__ ids, const float* __restrict__ we,
                     const float* __restrict__ pe, const float* __restrict__ te,
                     const float* __restrict__ g, const float* __restrict__ bb,
                     float* __restrict__ x, ushort* __restrict__ xb)
{
    int row = blockIdx.x * 4 + (threadIdx.x >> 6);
    int lane = threadIdx.x & 63;
    int l = row & (SEQ - 1);
    int id = ids[row];
    float vals[6];
    float s = 0.f;
    #pragma unroll
    for (int t = 0; t < 6; ++t) {
        int d = lane + 64 * t;
        float v = we[(size_t)id * DMODEL + d] + pe[(size_t)l * DMODEL + d] + te[d];
        vals[t] = v; s += v;
    }
    s = wave_reduce_sum(s);
    float m = s * (1.0f / DMODEL);
    float s2 = 0.f;
    #pragma unroll
    for (int t = 0; t < 6; ++t) { float dd = vals[t] - m; s2 += dd * dd; }
    s2 = wave_reduce_sum(s2);
    float rs = rsqrtf(s2 * (1.0f / DMODEL) + 1e-12f);
    #pragma unroll
    for (int t = 0; t < 6; ++t) {
        int d = lane + 64 * t;
        float val = (vals[t] - m) * rs * g[d] + bb[d];
        x[(size_t)row * DMODEL + d] = val;
        xb[(size_t)row * DMODEL + d] = f2bf(val);
    }
}

// ---------------------------------------------------------------- residual add + LN (in-place on fp32 x; bf16 branch r; writes xb too)
__global__ __launch_bounds__(256)
void add_ln_kernel(float* x, ushort* __restrict__ xb, const ushort* __restrict__ r,
                   const float* __restrict__ g, const float* __restrict__ bb)
{
    int row = blockIdx.x * 4 + (threadIdx.x >> 6);
    int lane = threadIdx.x & 63;
    float vals[6];
    float s = 0.f;
    #pragma unroll
    for (int t = 0; t < 6; ++t) {
        int d = lane + 64 * t;
        size_t idx = (size_t)row * DMODEL + d;
        float v = x[idx] + bf2f(r[idx]);
        vals[t] = v; s += v;
    }
    s = wave_reduce_sum(s);
    float m = s * (1.0f / DMODEL);
    float s2 = 0.f;
    #pragma unroll
    for (int t = 0; t < 6; ++t) { float dd = vals[t] - m; s2 += dd * dd; }
    s2 = wave_reduce_sum(s2);
    float rs = rsqrtf(s2 * (1.0f / DMODEL) + 1e-12f);
    #pragma unroll
    for (int t = 0; t < 6; ++t) {
        int d = lane + 64 * t;
        size_t idx = (size_t)row * DMODEL + d;
        float val = (vals[t] - m) * rs * g[d] + bb[d];
        x[idx] = val;
        xb[idx] = f2bf(val);
    }
}

// ---------------------------------------------------------------- bf16 MFMA GEMM, async-staged (m97 style)
// C[M,N] = A[M,K] @ W[K,N] + bias; A bf16 [M][K], WT bf16 [N][K].
// 128x128 tile, BK=64, 4 waves 2x2, global_load_lds(16B) staging into
// unpadded LDS with XOR k-seg swizzle (seg ^ (row&7)) -> 2-way banks (free).
template<typename TC>
__global__ __launch_bounds__(256)
void gemm_mfma(const ushort* __restrict__ A, const ushort* __restrict__ WT,
               const float* __restrict__ bias, TC* __restrict__ C,
               int M, int N, int K, int act)
{
    __shared__ __align__(16) ushort As[128 * 64];   // 16 KB
    __shared__ __align__(16) ushort Bs[128 * 64];   // 16 KB
    int tid = threadIdx.x;
    int lane = tid & 63, wv = tid >> 6;
    int waveM = wv >> 1, waveN = wv & 1;
    int lm = lane & 15, quad = lane >> 4;
    int row0 = blockIdx.x * 128, col0 = blockIdx.y * 128;
    int srow = lane >> 3, sseg = lane & 7;          // staging: 8 rows x 8 segs

    f32x4 acc[4][4] = {};

    for (int k0 = 0; k0 < K; k0 += 64) {
        __syncthreads();
        #pragma unroll
        for (int i = 0; i < 4; ++i) {
            int r = wv * 32 + i * 8 + srow;
            int sg = sseg ^ (r & 7);
            async16(A  + (size_t)(row0 + r) * K + k0 + sg * 8, &As[(wv * 32 + i * 8) * 64]);
            async16(WT + (size_t)(col0 + r) * K + k0 + sg * 8, &Bs[(wv * 32 + i * 8) * 64]);
        }
        __syncthreads();

        #pragma unroll
        for (int ks = 0; ks < 2; ++ks) {
            int physA = ((ks * 4 + quad) ^ (lm & 7)) * 8;
            bf16x8 af[4], bf[4];
            #pragma unroll
            for (int mt = 0; mt < 4; ++mt)
                af[mt] = *(const bf16x8*)&As[(waveM * 64 + mt * 16 + lm) * 64 + physA];
            #pragma unroll
            for (int nt = 0; nt < 4; ++nt)
                bf[nt] = *(const bf16x8*)&Bs[(waveN * 64 + nt * 16 + lm) * 64 + physA];
            #pragma unroll
            for (int mt = 0; mt < 4; ++mt)
                #pragma unroll
                for (int nt = 0; nt < 4; ++nt)
                    acc[mt][nt] = __builtin_amdgcn_mfma_f32_16x16x32_bf16(af[mt], bf[nt], acc[mt][nt], 0, 0, 0);
        }
    }

    // epilogue [layout verified R5]: row = quad*4 + reg, col = lm per 16x16 tile
    #pragma unroll
    for (int mt = 0; mt < 4; ++mt) {
        #pragma unroll
        for (int nt = 0; nt < 4; ++nt) {
            int col = col0 + waveN * 64 + nt * 16 + lm;
            float bv = bias[col];
            #pragma unroll
            for (int r = 0; r < 4; ++r) {
                int row = row0 + waveM * 64 + mt * 16 + quad * 4 + r;
                float val = acc[mt][nt][r] + bv;
                if (act == 1) val = gelu_tanh(gelu_tanh(val));
                if constexpr (sizeof(TC) == 2)
                    C[(size_t)row * N + col] = f2bf(val);
                else
                    C[(size_t)row * N + col] = val;
            }
        }
    }
}

// ---------------------------------------------------------------- beta: wave per row, coalesced bf16 x
__global__ __launch_bounds__(256)
void beta_kernel(const ushort* __restrict__ xb, const float* __restrict__ Wb,
                 const float* __restrict__ mask, float* __restrict__ beta)
{
    int row = blockIdx.x * 4 + (threadIdx.x >> 6);
    int lane = threadIdx.x & 63;
    float xr[6];
    #pragma unroll
    for (int t = 0; t < 6; ++t) xr[t] = bf2f(xb[(size_t)row * DMODEL + lane + 64 * t]);
    float mine = 0.f;
    #pragma unroll
    for (int h = 0; h < NH; ++h) {
        float p = 0.f;
        #pragma unroll
        for (int t = 0; t < 6; ++t) p += xr[t] * Wb[(size_t)(lane + 64 * t) * NH + h];
        p = wave_reduce_sum(p);
        if (lane == h) mine = p;
    }
    if (lane < NH) beta[(size_t)row * NH + lane] = sigmoidf(mine) * mask[row];
}

// ---------------------------------------------------------------- q/k l2norm: 32 lanes per head instance [verified R5]
__global__ __launch_bounds__(256)
void norm_qk_kernel(ushort* q, ushort* k, const float* __restrict__ mask)
{
    int hid = blockIdx.x * 8 + (threadIdx.x >> 5);
    int j = threadIdx.x & 31;
    int row = hid / NH;
    float mk = mask[row];
    size_t idx = (size_t)hid * DHEAD + j;

    float qv = bf2f(q[idx]);
    float ss = qv * qv;
    #pragma unroll
    for (int m = 1; m <= 16; m <<= 1) ss += __shfl_xor(ss, m, 32);
    q[idx] = f2bf(qv / (sqrtf(ss) + 1e-6f));

    float kv = bf2f(k[idx]);
    float ks = kv * kv;
    #pragma unroll
    for (int m = 1; m <= 16; m <<= 1) ks += __shfl_xor(ks, m, 32);
    k[idx] = f2bf((kv / (sqrtf(ks) + 1e-6f)) * mk);
}

// ---------------------------------------------------------------- delta-rule scan, v4
// One block (128 thr = 2 waves) per (b,h). Wave w owns columns [w*16,w*16+16);
// lane = (kq = lane>>4 in 0..3, n_local = lane&15). State Sf/Ss[8] covers
// k in [kq*8, kq*8+8) for column n. Cross-kq reduce: shfl_xor 16 then 32.
// LDS fp32 tiles, padded rows (36); o may alias v (tile staged first).
#define SCAN_T 32
#define SROW 36
__global__ __launch_bounds__(128)
void scan_kernel(const ushort* __restrict__ q, const ushort* __restrict__ k,
                 const ushort* __restrict__ v, const float* __restrict__ beta,
                 const float* __restrict__ dfast, const float* __restrict__ dslow,
                 ushort* __restrict__ o)
{
    __shared__ float qs[SCAN_T][SROW];
    __shared__ float ks[SCAN_T][SROW];
    __shared__ float vs[SCAN_T][SROW];
    __shared__ float bs[SCAN_T];

    int bh = blockIdx.x;
    int b = bh / NH, h = bh % NH;
    int tid = threadIdx.x;
    int w = tid >> 6, lane = tid & 63;
    int kq = lane >> 4, nl = lane & 15;
    int n = w * 16 + nl, kb0 = kq * 8;

    float gf = sigmoidf(dfast[h]);
    float gs = sigmoidf(dslow[h]);
    float Sf[8] = {}, Ss[8] = {};

    int srow = tid >> 2, sseg = tid & 3;   // staging: 32 rows x 4 segs of 8

    for (int t0 = 0; t0 < SEQ; t0 += SCAN_T) {
        __syncthreads();
        {
            size_t gaddr = ((size_t)(b * SEQ + t0 + srow) * NH + h) * DHEAD + sseg * 8;
            uint4 uq = *(const uint4*)(q + gaddr);
            uint4 uk = *(const uint4*)(k + gaddr);
            uint4 uv = *(const uint4*)(v + gaddr);
            ushort tq[8], tk[8], tv[8];
            *(uint4*)tq = uq; *(uint4*)tk = uk; *(uint4*)tv = uv;
            #pragma unroll
            for (int j = 0; j < 8; ++j) {
                qs[srow][sseg * 8 + j] = bf2f(tq[j]);
                ks[srow][sseg * 8 + j] = bf2f(tk[j]);
                vs[srow][sseg * 8 + j] = bf2f(tv[j]);
            }
        }
        if (tid < SCAN_T)
            bs[tid] = beta[(size_t)(b * SEQ + t0 + tid) * NH + h];
        __syncthreads();

        for (int t = 0; t < SCAN_T; ++t) {
            float kt[8], qt[8];
            *(float4*)&kt[0] = *(const float4*)&ks[t][kb0 + 0];
            *(float4*)&kt[4] = *(const float4*)&ks[t][kb0 + 4];
            *(float4*)&qt[0] = *(const float4*)&qs[t][kb0 + 0];
            *(float4*)&qt[4] = *(const float4*)&qs[t][kb0 + 4];
            float vt = vs[t][n], bt = bs[t];

            float pf[8], ps[8];
            #pragma unroll
            for (int j = 0; j < 8; ++j) { pf[j] = kt[j] * Sf[j]; ps[j] = kt[j] * Ss[j]; }
            #pragma unroll
            for (int off = 4; off >= 1; off >>= 1)
                #pragma unroll
                for (int j = 0; j < off; ++j) { pf[j] += pf[j + off]; ps[j] += ps[j + off]; }
            float pft = pf[0], pst = ps[0];
            pft += __shfl_xor(pft, 16, 64); pft += __shfl_xor(pft, 32, 64);
            pst += __shfl_xor(pst, 16, 64); pst += __shfl_xor(pst, 32, 64);

            float cf = bt * (vt - pft), cs = bt * (vt - pst);
            float ot[8];
            #pragma unroll
            for (int j = 0; j < 8; ++j) {
                Sf[j] = gf * Sf[j] + kt[j] * cf;
                Ss[j] = gs * Ss[j] + kt[j] * cs;
                ot[j] = qt[j] * (Sf[j] + Ss[j]);
            }
            #pragma unroll
            for (int off = 4; off >= 1; off >>= 1)
                #pragma unroll
                for (int j = 0; j < off; ++j) ot[j] += ot[j + off];
            float ott = ot[0];
            ott += __shfl_xor(ott, 16, 64); ott += __shfl_xor(ott, 32, 64);
            if (kq == 0)
                o[((size_t)(b * SEQ + t0 + t) * NH + h) * DHEAD + n] = f2bf(0.5f * ott);
        }
    }
}

// ---------------------------------------------------------------- masked mean-pool + l2 normalize
__global__ __launch_bounds__(384)
void pool_kernel(const float* __restrict__ x, const float* __restrict__ mask,
                 float* __restrict__ out)
{
    int b = blockIdx.x;
    int d = threadIdx.x;
    float acc = 0.f, msum = 0.f;
    for (int l = 0; l < SEQ; ++l) {
        float mk = mask[b * SEQ + l];
        acc += x[((size_t)b * SEQ + l) * DMODEL + d] * mk;
        msum += mk;
    }
    float emb = acc / fmaxf(msum, 1e-9f);
    __shared__ float red[6];
    float ss = wave_reduce_sum(emb * emb);
    int wvi = d >> 6, ln = d & 63;
    if (ln == 0) red[wvi] = ss;
    __syncthreads();
    float tot = 0.f;
    #pragma unroll
    for (int i = 0; i < 6; ++i) tot += red[i];
    float nrm = fmaxf(sqrtf(tot), 1e-12f);
    out[(size_t)b * DMODEL + d] = emb / nrm;
}

// ---------------------------------------------------------------- launch

extern "C" void kernel_launch(void* const* d_in, const int* in_sizes, int n_in,
                              void* d_out, int out_size, void* d_ws, size_t ws_size,
                              hipStream_t stream)
{
    const int*   ids   = (const int*)d_in[0];
    const float* mask  = (const float*)d_in[1];
    const float* we    = (const float*)d_in[2];
    const float* pe    = (const float*)d_in[3];
    const float* te    = (const float*)d_in[4];
    const float* elg   = (const float*)d_in[5];
    const float* elb   = (const float*)d_in[6];
    const float* Wq    = (const float*)d_in[7];
    const float* bq    = (const float*)d_in[8];
    const float* Wk    = (const float*)d_in[9];
    const float* bk    = (const float*)d_in[10];
    const float* Wv    = (const float*)d_in[11];
    const float* bv    = (const float*)d_in[12];
    const float* Wb    = (const float*)d_in[13];
    const float* dfast = (const float*)d_in[14];
    const float* dslow = (const float*)d_in[15];
    const float* Wo    = (const float*)d_in[16];
    const float* bo    = (const float*)d_in[17];
    const float* l1g   = (const float*)d_in[18];
    const float* l1b   = (const float*)d_in[19];
    const float* W1    = (const float*)d_in[20];
    const float* b1    = (const float*)d_in[21];
    const float* W2    = (const float*)d_in[22];
    const float* b2    = (const float*)d_in[23];
    const float* l2g   = (const float*)d_in[24];
    const float* l2b   = (const float*)d_in[25];
    float* out = (float*)d_out;

    // ---- workspace: 199.0 MB total (known-good ceiling: 202.9 MB, R4) ----
    const size_t RD = (size_t)NROWS * DMODEL;    // 12,582,912 elements
    float* x     = (float*)d_ws;                 // fp32 residual      (50.33 MB)
    float* betab = x + RD;                       // fp32 [NROWS,NH]    ( 1.57 MB)
    ushort* xb   = (ushort*)(betab + (size_t)NROWS * NH);  // bf16 residual copy (25.17)
    ushort* qb   = xb + RD;                      // bf16 (25.17 MB)
    ushort* kb   = qb + RD;                      // bf16; FFN-h chunk reuses (25.17)
    ushort* vb   = kb + RD;                      // bf16; o in-place   (25.17 MB)
    ushort* ab   = vb + RD;                      // bf16 branch out    (25.17 MB)
    ushort* WqT  = ab + RD;                      // transposed bf16 weights: 21.23 MB
    ushort* WkT  = WqT + (size_t)NLAYER * DMODEL * DMODEL;
    ushort* WvT  = WkT + (size_t)NLAYER * DMODEL * DMODEL;
    ushort* WoT  = WvT + (size_t)NLAYER * DMODEL * DMODEL;
    ushort* W1T  = WoT + (size_t)NLAYER * DMODEL * DMODEL;   // [1536][384]
    ushort* W2T  = W1T + (size_t)NLAYER * DMODEL * DFFN;     // [384][1536]

    dim3 blk256(256);
    dim3 rowsGrid(NROWS / 4);
    dim3 gemmGrid_D(NROWS / 128, DMODEL / 128);      // (256, 3)
    dim3 gemmGrid_C1(FFN_CHUNK / 128, DFFN / 128);   // (64, 12)
    dim3 gemmGrid_C2(FFN_CHUNK / 128, DMODEL / 128); // (64, 3)
    dim3 chunkRows(FFN_CHUNK / 4);
    dim3 normGrid(NROWS * NH / 8);                   // 49152 blocks
    dim3 scanGrid(BATCH * NH);                       // 768 blocks x 128 thr

    convT_kernel<<<dim3(12, 12, NLAYER), blk256, 0, stream>>>(Wq, WqT, DMODEL, DMODEL);
    convT_kernel<<<dim3(12, 12, NLAYER), blk256, 0, stream>>>(Wk, WkT, DMODEL, DMODEL);
    convT_kernel<<<dim3(12, 12, NLAYER), blk256, 0, stream>>>(Wv, WvT, DMODEL, DMODEL);
    convT_kernel<<<dim3(12, 12, NLAYER), blk256, 0, stream>>>(Wo, WoT, DMODEL, DMODEL);
    convT_kernel<<<dim3(12, 48, NLAYER), blk256, 0, stream>>>(W1, W1T, DMODEL, DFFN);
    convT_kernel<<<dim3(48, 12, NLAYER), blk256, 0, stream>>>(W2, W2T, DFFN, DMODEL);

    embed_ln_kernel<<<rowsGrid, blk256, 0, stream>>>(ids, we, pe, te, elg, elb, x, xb);

    for (int i = 0; i < NLAYER; ++i) {
        const ushort* WqT_i = WqT + (size_t)i * DMODEL * DMODEL;
        const ushort* WkT_i = WkT + (size_t)i * DMODEL * DMODEL;
        const ushort* WvT_i = WvT + (size_t)i * DMODEL * DMODEL;
        const ushort* WoT_i = WoT + (size_t)i * DMODEL * DMODEL;
        const float*  Wb_i  = Wb  + (size_t)i * DMODEL * NH;
        const ushort* W1T_i = W1T + (size_t)i * DMODEL * DFFN;
        const ushort* W2T_i = W2T + (size_t)i * DFFN * DMODEL;

        gemm_mfma<ushort><<<gemmGrid_D, blk256, 0, stream>>>(xb, WqT_i, bq + i * DMODEL, qb,
                                                             NROWS, DMODEL, DMODEL, 0);
        gemm_mfma<ushort><<<gemmGrid_D, blk256, 0, stream>>>(xb, WkT_i, bk + i * DMODEL, kb,
                                                             NROWS, DMODEL, DMODEL, 0);
        gemm_mfma<ushort><<<gemmGrid_D, blk256, 0, stream>>>(xb, WvT_i, bv + i * DMODEL, vb,
                                                             NROWS, DMODEL, DMODEL, 0);
        beta_kernel<<<rowsGrid, blk256, 0, stream>>>(xb, Wb_i, mask, betab);
        norm_qk_kernel<<<normGrid, blk256, 0, stream>>>(qb, kb, mask);
        scan_kernel<<<scanGrid, dim3(128), 0, stream>>>(qb, kb, vb, betab,
                                                        dfast + i * NH, dslow + i * NH, vb);
        gemm_mfma<ushort><<<gemmGrid_D, blk256, 0, stream>>>(vb, WoT_i, bo + i * DMODEL, ab,
                                                             NROWS, DMODEL, DMODEL, 0);
        add_ln_kernel<<<rowsGrid, blk256, 0, stream>>>(x, xb, ab, l1g + i * DMODEL, l1b + i * DMODEL);

        for (int c = 0; c < NROWS / FFN_CHUNK; ++c) {
            const ushort* xc = xb + (size_t)c * FFN_CHUNK * DMODEL;
            ushort* abc = ab + (size_t)c * FFN_CHUNK * DMODEL;
            gemm_mfma<ushort><<<gemmGrid_C1, blk256, 0, stream>>>(xc, W1T_i, b1 + i * DFFN, kb,
                                                                  FFN_CHUNK, DFFN, DMODEL, 1);
            gemm_mfma<ushort><<<gemmGrid_C2, blk256, 0, stream>>>(kb, W2T_i, b2 + i * DMODEL, abc,
                                                                  FFN_CHUNK, DMODEL, DFFN, 0);
            add_ln_kernel<<<chunkRows, blk256, 0, stream>>>(x + (size_t)c * FFN_CHUNK * DMODEL,
                                                            xb + (size_t)c * FFN_CHUNK * DMODEL, abc,
                                                            l2g + i * DMODEL, l2b + i * DMODEL);
        }
    }

    pool_kernel<<<dim3(BATCH), dim3(384), 0, stream>>>(x, mask, out);
}

// Round 9
// 4187.006 us; speedup vs baseline: 4.6508x; 1.0505x over previous
//
#include <hip/hip_runtime.h>
#include <cstdint>
#include <cstddef>
#include <cmath>

#define NLAYER 6
#define NH 12
#define DMODEL 384
#define DHEAD 32
#define DFFN 1536
#define BATCH 64
#define SEQ 512
#define NROWS (BATCH*SEQ)   // 32768
#define DQKV 1152           // fused q|k|v row length
#define FFN_CHUNK 8192      // 4 chunks

typedef unsigned short ushort;
typedef __attribute__((ext_vector_type(8))) short bf16x8;   // 8 bf16 = 4 VGPRs
typedef __attribute__((ext_vector_type(4))) float f32x4;

// ---------------------------------------------------------------- utilities

__device__ inline float bf2f(ushort u) {
    union { unsigned int i; float f; } c; c.i = ((unsigned int)u) << 16; return c.f;
}
__device__ inline ushort f2bf(float f) {
    union { float f; unsigned int i; } c; c.f = f;
    unsigned int i = c.i;
    unsigned int lsb = (i >> 16) & 1u;
    i += 0x7fffu + lsb;          // round-to-nearest-even
    return (ushort)(i >> 16);
}

__device__ inline float wave_reduce_sum(float v) {
    #pragma unroll
    for (int m = 32; m >= 1; m >>= 1) v += __shfl_xor(v, m, 64);
    return v;
}

__device__ inline float sigmoidf(float x) { return 1.0f / (1.0f + expf(-x)); }

__device__ inline float gelu_tanh(float x) {
    const float c = 0.7978845608028654f; // sqrt(2/pi)
    float t = tanhf(c * (x + 0.044715f * x * x * x));
    return 0.5f * x * (1.0f + t);
}

// async global->LDS, 16 bytes per lane; lds base must be wave-uniform
__device__ inline void async16(const ushort* g, ushort* l) {
    __builtin_amdgcn_global_load_lds(
        (const __attribute__((address_space(1))) unsigned int*)g,
        (__attribute__((address_space(3))) unsigned int*)l,
        16, 0, 0);
}

// ---------------------------------------------------------------- weight convert+transpose
// W fp32 [L][K][N] -> WT bf16 rows of K elements; layer stride lStride,
// dest row offset nOff (fused QKV packing).
__global__ __launch_bounds__(256)
void convT_kernel(const float* __restrict__ W, ushort* __restrict__ WT, int K, int N,
                  size_t lStride, int nOff)
{
    __shared__ float t[32][33];
    int k0 = blockIdx.x * 32, n0 = blockIdx.y * 32, L = blockIdx.z;
    const float* Wl = W + (size_t)L * K * N;
    ushort* WTl = WT + (size_t)L * lStride;
    int tx = threadIdx.x & 31, ty = threadIdx.x >> 5;   // 32 x 8
    #pragma unroll
    for (int i = 0; i < 4; ++i)
        t[ty + 8 * i][tx] = Wl[(size_t)(k0 + ty + 8 * i) * N + n0 + tx];
    __syncthreads();
    #pragma unroll
    for (int i = 0; i < 4; ++i)
        WTl[(size_t)(nOff + n0 + ty + 8 * i) * K + k0 + tx] = f2bf(t[tx][ty + 8 * i]);
}

// ---------------------------------------------------------------- fused qkv bias concat: [L][1152]
__global__ __launch_bounds__(384)
void biascat_kernel(const float* __restrict__ bq, const float* __restrict__ bk,
                    const float* __restrict__ bv, float* __restrict__ dst)
{
    int L = blockIdx.x, d = threadIdx.x;
    dst[(size_t)L * DQKV + d]             = bq[(size_t)L * DMODEL + d];
    dst[(size_t)L * DQKV + DMODEL + d]    = bk[(size_t)L * DMODEL + d];
    dst[(size_t)L * DQKV + 2*DMODEL + d]  = bv[(size_t)L * DMODEL + d];
}

// ---------------------------------------------------------------- embedding + LN (writes fp32 x and bf16 xb)
__global__ __launch_bounds__(256)
void embed_ln_kernel(const int* __restrict__ ids, const float* __restrict__ we,
                     const float* __restrict__ pe, const float* __restrict__ te,
                     const float* __restrict__ g, const float* __restrict__ bb,
                     float* __restrict__ x, ushort* __restrict__ xb)
{
    int row = blockIdx.x * 4 + (threadIdx.x >> 6);
    int lane = threadIdx.x & 63;
    int l = row & (SEQ - 1);
    int id = ids[row];
    float vals[6];
    float s = 0.f;
    #pragma unroll
    for (int t = 0; t < 6; ++t) {
        int d = lane + 64 * t;
        float v = we[(size_t)id * DMODEL + d] + pe[(size_t)l * DMODEL + d] + te[d];
        vals[t] = v; s += v;
    }
    s = wave_reduce_sum(s);
    float m = s * (1.0f / DMODEL);
    float s2 = 0.f;
    #pragma unroll
    for (int t = 0; t < 6; ++t) { float dd = vals[t] - m; s2 += dd * dd; }
    s2 = wave_reduce_sum(s2);
    float rs = rsqrtf(s2 * (1.0f / DMODEL) + 1e-12f);
    #pragma unroll
    for (int t = 0; t < 6; ++t) {
        int d = lane + 64 * t;
        float val = (vals[t] - m) * rs * g[d] + bb[d];
        x[(size_t)row * DMODEL + d] = val;
        xb[(size_t)row * DMODEL + d] = f2bf(val);
    }
}

// ---------------------------------------------------------------- residual add + LN (fp32 x in-place; bf16 branch; writes xb)
__global__ __launch_bounds__(256)
void add_ln_kernel(float* x, ushort* __restrict__ xb, const ushort* __restrict__ r,
                   const float* __restrict__ g, const float* __restrict__ bb)
{
    int row = blockIdx.x * 4 + (threadIdx.x >> 6);
    int lane = threadIdx.x & 63;
    float vals[6];
    float s = 0.f;
    #pragma unroll
    for (int t = 0; t < 6; ++t) {
        int d = lane + 64 * t;
        size_t idx = (size_t)row * DMODEL + d;
        float v = x[idx] + bf2f(r[idx]);
        vals[t] = v; s += v;
    }
    s = wave_reduce_sum(s);
    float m = s * (1.0f / DMODEL);
    float s2 = 0.f;
    #pragma unroll
    for (int t = 0; t < 6; ++t) { float dd = vals[t] - m; s2 += dd * dd; }
    s2 = wave_reduce_sum(s2);
    float rs = rsqrtf(s2 * (1.0f / DMODEL) + 1e-12f);
    #pragma unroll
    for (int t = 0; t < 6; ++t) {
        int d = lane + 64 * t;
        size_t idx = (size_t)row * DMODEL + d;
        float val = (vals[t] - m) * rs * g[d] + bb[d];
        x[idx] = val;
        xb[idx] = f2bf(val);
    }
}

// ---------------------------------------------------------------- bf16 MFMA GEMM, async-staged  [verified R7]
// A row stride Astride (elements) may differ from K (strided o-section reads).
template<typename TC>
__global__ __launch_bounds__(256)
void gemm_mfma(const ushort* __restrict__ A, const ushort* __restrict__ WT,
               const float* __restrict__ bias, TC* __restrict__ C,
               int M, int N, int K, int Astride, int act)
{
    __shared__ __align__(16) ushort As[128 * 64];   // 16 KB
    __shared__ __align__(16) ushort Bs[128 * 64];   // 16 KB
    int tid = threadIdx.x;
    int lane = tid & 63, wv = tid >> 6;
    int waveM = wv >> 1, waveN = wv & 1;
    int lm = lane & 15, quad = lane >> 4;
    int row0 = blockIdx.x * 128, col0 = blockIdx.y * 128;
    int srow = lane >> 3, sseg = lane & 7;          // staging: 8 rows x 8 segs

    f32x4 acc[4][4] = {};

    for (int k0 = 0; k0 < K; k0 += 64) {
        __syncthreads();
        #pragma unroll
        for (int i = 0; i < 4; ++i) {
            int r = wv * 32 + i * 8 + srow;
            int sg = sseg ^ (r & 7);
            async16(A  + (size_t)(row0 + r) * Astride + k0 + sg * 8, &As[(wv * 32 + i * 8) * 64]);
            async16(WT + (size_t)(col0 + r) * K + k0 + sg * 8, &Bs[(wv * 32 + i * 8) * 64]);
        }
        __syncthreads();

        #pragma unroll
        for (int ks = 0; ks < 2; ++ks) {
            int physA = ((ks * 4 + quad) ^ (lm & 7)) * 8;
            bf16x8 af[4], bf[4];
            #pragma unroll
            for (int mt = 0; mt < 4; ++mt)
                af[mt] = *(const bf16x8*)&As[(waveM * 64 + mt * 16 + lm) * 64 + physA];
            #pragma unroll
            for (int nt = 0; nt < 4; ++nt)
                bf[nt] = *(const bf16x8*)&Bs[(waveN * 64 + nt * 16 + lm) * 64 + physA];
            #pragma unroll
            for (int mt = 0; mt < 4; ++mt)
                #pragma unroll
                for (int nt = 0; nt < 4; ++nt)
                    acc[mt][nt] = __builtin_amdgcn_mfma_f32_16x16x32_bf16(af[mt], bf[nt], acc[mt][nt], 0, 0, 0);
        }
    }

    #pragma unroll
    for (int mt = 0; mt < 4; ++mt) {
        #pragma unroll
        for (int nt = 0; nt < 4; ++nt) {
            int col = col0 + waveN * 64 + nt * 16 + lm;
            float bv = bias[col];
            #pragma unroll
            for (int r = 0; r < 4; ++r) {
                int row = row0 + waveM * 64 + mt * 16 + quad * 4 + r;
                float val = acc[mt][nt][r] + bv;
                if (act == 1) val = gelu_tanh(gelu_tanh(val));
                if constexpr (sizeof(TC) == 2)
                    C[(size_t)row * N + col] = f2bf(val);
                else
                    C[(size_t)row * N + col] = val;
            }
        }
    }
}

// ---------------------------------------------------------------- beta: wave per row, coalesced bf16 x  [verified R7]
__global__ __launch_bounds__(256)
void beta_kernel(const ushort* __restrict__ xb, const float* __restrict__ Wb,
                 const float* __restrict__ mask, float* __restrict__ beta)
{
    int row = blockIdx.x * 4 + (threadIdx.x >> 6);
    int lane = threadIdx.x & 63;
    float xr[6];
    #pragma unroll
    for (int t = 0; t < 6; ++t) xr[t] = bf2f(xb[(size_t)row * DMODEL + lane + 64 * t]);
    float mine = 0.f;
    #pragma unroll
    for (int h = 0; h < NH; ++h) {
        float p = 0.f;
        #pragma unroll
        for (int t = 0; t < 6; ++t) p += xr[t] * Wb[(size_t)(lane + 64 * t) * NH + h];
        p = wave_reduce_sum(p);
        if (lane == h) mine = p;
    }
    if (lane < NH) beta[(size_t)row * NH + lane] = sigmoidf(mine) * mask[row];
}

// ---------------------------------------------------------------- q/k l2norm on fused qkv buffer (stride DQKV)
__global__ __launch_bounds__(256)
void norm_qk_kernel(ushort* qkv, const float* __restrict__ mask)
{
    int hid = blockIdx.x * 8 + (threadIdx.x >> 5);
    int j = threadIdx.x & 31;
    int row = hid / NH, h = hid % NH;
    float mk = mask[row];
    size_t base = (size_t)row * DQKV + h * DHEAD + j;
    ushort* qp = qkv + base;
    ushort* kp = qkv + base + DMODEL;

    float qv = bf2f(*qp);
    float ss = qv * qv;
    #pragma unroll
    for (int m = 1; m <= 16; m <<= 1) ss += __shfl_xor(ss, m, 32);
    *qp = f2bf(qv / (sqrtf(ss) + 1e-6f));

    float kv = bf2f(*kp);
    float ks = kv * kv;
    #pragma unroll
    for (int m = 1; m <= 16; m <<= 1) ks += __shfl_xor(ks, m, 32);
    *kp = f2bf((kv / (sqrtf(ks) + 1e-6f)) * mk);
}

// ---------------------------------------------------------------- delta-rule scan v5: zero cross-lane ops
// One wave per 2 (b,h); lane = (half -> which bh, n = column). Lane owns the
// FULL 32-deep k state for column n (float2-packed: v_pk_fma). kt/qt are
// wave-broadcast LDS reads independent of state -> prefetchable.
// o writes into the q-section of qkv (q rows staged before overwrite; safe).
#define SCAN_T 32
#define SROW 36
__global__ __launch_bounds__(64)
void scan_kernel(const ushort* __restrict__ qkv, const float* __restrict__ beta,
                 const float* __restrict__ dfast, const float* __restrict__ dslow,
                 ushort* __restrict__ o)
{
    __shared__ float qs[2][SCAN_T][SROW];
    __shared__ float ks[2][SCAN_T][SROW];
    __shared__ float vs[2][SCAN_T][SROW];
    __shared__ float bs[2][SCAN_T];

    int gw = blockIdx.x;
    int lane = threadIdx.x;
    int half = lane >> 5, n = lane & 31;
    int bh0 = gw * 2, bh1 = gw * 2 + 1;
    int bA = bh0 / NH, hA = bh0 % NH;
    int bB = bh1 / NH, hB = bh1 % NH;
    int myb = half ? bB : bA, myh = half ? hB : hA;

    float gf = sigmoidf(dfast[myh]);
    float gsl = sigmoidf(dslow[myh]);
    float2 gf2 = make_float2(gf, gf), gs2 = make_float2(gsl, gsl);
    float2 Sf[16], Ss[16];
    #pragma unroll
    for (int j = 0; j < 16; ++j) { Sf[j] = make_float2(0.f, 0.f); Ss[j] = make_float2(0.f, 0.f); }

    for (int t0 = 0; t0 < SEQ; t0 += SCAN_T) {
        __syncthreads();
        {
            // lane stages row n of its half's bh: 32 bf16 per tensor
            size_t rbase = (size_t)(myb * SEQ + t0 + n) * DQKV + myh * DHEAD;
            #pragma unroll
            for (int s = 0; s < 4; ++s) {
                uint4 uq = *(const uint4*)(qkv + rbase + s * 8);
                uint4 uk = *(const uint4*)(qkv + rbase + DMODEL + s * 8);
                uint4 uv = *(const uint4*)(qkv + rbase + 2 * DMODEL + s * 8);
                ushort tq[8], tk[8], tv[8];
                *(uint4*)tq = uq; *(uint4*)tk = uk; *(uint4*)tv = uv;
                #pragma unroll
                for (int j = 0; j < 8; ++j) {
                    qs[half][n][s * 8 + j] = bf2f(tq[j]);
                    ks[half][n][s * 8 + j] = bf2f(tk[j]);
                    vs[half][n][s * 8 + j] = bf2f(tv[j]);
                }
            }
            bs[half][n] = beta[(size_t)(myb * SEQ + t0 + n) * NH + myh];
        }
        __syncthreads();

        #pragma unroll 4
        for (int t = 0; t < SCAN_T; ++t) {
            float2 kt[16], qt[16];
            #pragma unroll
            for (int s = 0; s < 8; ++s) {
                *(float4*)&kt[s * 2] = *(const float4*)&ks[half][t][s * 4];
                *(float4*)&qt[s * 2] = *(const float4*)&qs[half][t][s * 4];
            }
            float vt = vs[half][t][n], bt = bs[half][t];

            float2 pf0 = kt[0] * Sf[0], pf1 = kt[1] * Sf[1], pf2 = kt[2] * Sf[2], pf3 = kt[3] * Sf[3];
            float2 ps0 = kt[0] * Ss[0], ps1 = kt[1] * Ss[1], ps2 = kt[2] * Ss[2], ps3 = kt[3] * Ss[3];
            #pragma unroll
            for (int j = 4; j < 16; j += 4) {
                pf0 += kt[j] * Sf[j];     pf1 += kt[j + 1] * Sf[j + 1];
                pf2 += kt[j + 2] * Sf[j + 2]; pf3 += kt[j + 3] * Sf[j + 3];
                ps0 += kt[j] * Ss[j];     ps1 += kt[j + 1] * Ss[j + 1];
                ps2 += kt[j + 2] * Ss[j + 2]; ps3 += kt[j + 3] * Ss[j + 3];
            }
            float2 pfv = (pf0 + pf1) + (pf2 + pf3);
            float2 psv = (ps0 + ps1) + (ps2 + ps3);
            float pft = pfv.x + pfv.y, pst = psv.x + psv.y;

            float cf = bt * (vt - pft), cs = bt * (vt - pst);
            float2 cf2 = make_float2(cf, cf), cs2 = make_float2(cs, cs);

            float2 o0 = make_float2(0.f, 0.f), o1 = o0, o2 = o0, o3 = o0;
            #pragma unroll
            for (int j = 0; j < 16; j += 4) {
                Sf[j] = gf2 * Sf[j] + kt[j] * cf2;         Ss[j] = gs2 * Ss[j] + kt[j] * cs2;
                Sf[j+1] = gf2 * Sf[j+1] + kt[j+1] * cf2;   Ss[j+1] = gs2 * Ss[j+1] + kt[j+1] * cs2;
                Sf[j+2] = gf2 * Sf[j+2] + kt[j+2] * cf2;   Ss[j+2] = gs2 * Ss[j+2] + kt[j+2] * cs2;
                Sf[j+3] = gf2 * Sf[j+3] + kt[j+3] * cf2;   Ss[j+3] = gs2 * Ss[j+3] + kt[j+3] * cs2;
                o0 += qt[j] * (Sf[j] + Ss[j]);
                o1 += qt[j+1] * (Sf[j+1] + Ss[j+1]);
                o2 += qt[j+2] * (Sf[j+2] + Ss[j+2]);
                o3 += qt[j+3] * (Sf[j+3] + Ss[j+3]);
            }
            float2 ov = (o0 + o1) + (o2 + o3);
            float ott = ov.x + ov.y;
            // o into q-section of qkv: row stride DQKV
            o[((size_t)(myb * SEQ + t0 + t)) * DQKV + myh * DHEAD + n] = f2bf(0.5f * ott);
        }
    }
}

// ---------------------------------------------------------------- masked mean-pool + l2 normalize
__global__ __launch_bounds__(384)
void pool_kernel(const float* __restrict__ x, const float* __restrict__ mask,
                 float* __restrict__ out)
{
    int b = blockIdx.x;
    int d = threadIdx.x;
    float acc = 0.f, msum = 0.f;
    for (int l = 0; l < SEQ; ++l) {
        float mk = mask[b * SEQ + l];
        acc += x[((size_t)b * SEQ + l) * DMODEL + d] * mk;
        msum += mk;
    }
    float emb = acc / fmaxf(msum, 1e-9f);
    __shared__ float red[6];
    float ss = wave_reduce_sum(emb * emb);
    int wvi = d >> 6, ln = d & 63;
    if (ln == 0) red[wvi] = ss;
    __syncthreads();
    float tot = 0.f;
    #pragma unroll
    for (int i = 0; i < 6; ++i) tot += red[i];
    float nrm = fmaxf(sqrtf(tot), 1e-12f);
    out[(size_t)b * DMODEL + d] = emb / nrm;
}

// ---------------------------------------------------------------- launch

extern "C" void kernel_launch(void* const* d_in, const int* in_sizes, int n_in,
                              void* d_out, int out_size, void* d_ws, size_t ws_size,
                              hipStream_t stream)
{
    const int*   ids   = (const int*)d_in[0];
    const float* mask  = (const float*)d_in[1];
    const float* we    = (const float*)d_in[2];
    const float* pe    = (const float*)d_in[3];
    const float* te    = (const float*)d_in[4];
    const float* elg   = (const float*)d_in[5];
    const float* elb   = (const float*)d_in[6];
    const float* Wq    = (const float*)d_in[7];
    const float* bq    = (const float*)d_in[8];
    const float* Wk    = (const float*)d_in[9];
    const float* bk    = (const float*)d_in[10];
    const float* Wv    = (const float*)d_in[11];
    const float* bv    = (const float*)d_in[12];
    const float* Wb    = (const float*)d_in[13];
    const float* dfast = (const float*)d_in[14];
    const float* dslow = (const float*)d_in[15];
    const float* Wo    = (const float*)d_in[16];
    const float* bo    = (const float*)d_in[17];
    const float* l1g   = (const float*)d_in[18];
    const float* l1b   = (const float*)d_in[19];
    const float* W1    = (const float*)d_in[20];
    const float* b1    = (const float*)d_in[21];
    const float* W2    = (const float*)d_in[22];
    const float* b2    = (const float*)d_in[23];
    const float* l2g   = (const float*)d_in[24];
    const float* l2b   = (const float*)d_in[25];
    float* out = (float*)d_out;

    // ---- workspace: 199.0 MB total (proven ceiling 202.9 MB, R4) ----
    const size_t RD = (size_t)NROWS * DMODEL;    // 12,582,912 elements
    float* x      = (float*)d_ws;                      // 50.33 MB
    float* betab  = x + RD;                            //  1.57 MB
    ushort* xb    = (ushort*)(betab + (size_t)NROWS * NH);   // 25.17 MB
    ushort* qkvb  = xb + RD;                           // 75.50 MB  [row][1152]
    ushort* ab    = qkvb + (size_t)NROWS * DQKV;       // 25.17 MB (attn out / FFN h-chunk)
    ushort* WqkvT = ab + RD;                           //  5.31 MB [L][1152][384]
    ushort* WoT   = WqkvT + (size_t)NLAYER * DQKV * DMODEL;  // 1.77 MB
    ushort* W1T   = WoT + (size_t)NLAYER * DMODEL * DMODEL;  // 7.08 MB [L][1536][384]
    ushort* W2T   = W1T + (size_t)NLAYER * DMODEL * DFFN;    // 7.08 MB [L][384][1536]
    float* biasqkv = (float*)(W2T + (size_t)NLAYER * DFFN * DMODEL); // 27 KB

    dim3 blk256(256);
    dim3 rowsGrid(NROWS / 4);
    dim3 gemmGrid_QKV(NROWS / 128, DQKV / 128);      // (256, 9)
    dim3 gemmGrid_D(NROWS / 128, DMODEL / 128);      // (256, 3)
    dim3 gemmGrid_C1(FFN_CHUNK / 128, DFFN / 128);   // (64, 12)
    dim3 gemmGrid_C2(FFN_CHUNK / 128, DMODEL / 128); // (64, 3)
    dim3 chunkRows(FFN_CHUNK / 4);
    dim3 normGrid(NROWS * NH / 8);                   // 49152 blocks
    dim3 scanGrid(BATCH * NH / 2);                   // 384 single-wave blocks

    const size_t lsQKV = (size_t)DQKV * DMODEL;
    convT_kernel<<<dim3(12, 12, NLAYER), blk256, 0, stream>>>(Wq, WqkvT, DMODEL, DMODEL, lsQKV, 0);
    convT_kernel<<<dim3(12, 12, NLAYER), blk256, 0, stream>>>(Wk, WqkvT, DMODEL, DMODEL, lsQKV, DMODEL);
    convT_kernel<<<dim3(12, 12, NLAYER), blk256, 0, stream>>>(Wv, WqkvT, DMODEL, DMODEL, lsQKV, 2*DMODEL);
    convT_kernel<<<dim3(12, 12, NLAYER), blk256, 0, stream>>>(Wo, WoT, DMODEL, DMODEL, (size_t)DMODEL*DMODEL, 0);
    convT_kernel<<<dim3(12, 48, NLAYER), blk256, 0, stream>>>(W1, W1T, DMODEL, DFFN, (size_t)DMODEL*DFFN, 0);
    convT_kernel<<<dim3(48, 12, NLAYER), blk256, 0, stream>>>(W2, W2T, DFFN, DMODEL, (size_t)DFFN*DMODEL, 0);
    biascat_kernel<<<dim3(NLAYER), dim3(384), 0, stream>>>(bq, bk, bv, biasqkv);

    embed_ln_kernel<<<rowsGrid, blk256, 0, stream>>>(ids, we, pe, te, elg, elb, x, xb);

    for (int i = 0; i < NLAYER; ++i) {
        const ushort* WqkvT_i = WqkvT + (size_t)i * lsQKV;
        const ushort* WoT_i   = WoT + (size_t)i * DMODEL * DMODEL;
        const float*  Wb_i    = Wb  + (size_t)i * DMODEL * NH;
        const ushort* W1T_i   = W1T + (size_t)i * DMODEL * DFFN;
        const ushort* W2T_i   = W2T + (size_t)i * DFFN * DMODEL;

        gemm_mfma<ushort><<<gemmGrid_QKV, blk256, 0, stream>>>(xb, WqkvT_i, biasqkv + (size_t)i * DQKV,
                                                               qkvb, NROWS, DQKV, DMODEL, DMODEL, 0);
        beta_kernel<<<rowsGrid, blk256, 0, stream>>>(xb, Wb_i, mask, betab);
        norm_qk_kernel<<<normGrid, blk256, 0, stream>>>(qkvb, mask);
        // o overwrites q-section of qkvb (stride DQKV)
        scan_kernel<<<scanGrid, dim3(64), 0, stream>>>(qkvb, betab,
                                                       dfast + i * NH, dslow + i * NH, qkvb);
        // Wo GEMM reads strided o (Astride = DQKV)
        gemm_mfma<ushort><<<gemmGrid_D, blk256, 0, stream>>>(qkvb, WoT_i, bo + i * DMODEL, ab,
                                                             NROWS, DMODEL, DMODEL, DQKV, 0);
        add_ln_kernel<<<rowsGrid, blk256, 0, stream>>>(x, xb, ab, l1g + i * DMODEL, l1b + i * DMODEL);

        // FFN in 4 chunks: h -> ab (dead), W2-out -> qkvb front (dead)
        for (int c = 0; c < NROWS / FFN_CHUNK; ++c) {
            const ushort* xc = xb + (size_t)c * FFN_CHUNK * DMODEL;
            ushort* w2out = qkvb + (size_t)c * FFN_CHUNK * DMODEL;
            gemm_mfma<ushort><<<gemmGrid_C1, blk256, 0, stream>>>(xc, W1T_i, b1 + i * DFFN, ab,
                                                                  FFN_CHUNK, DFFN, DMODEL, DMODEL, 1);
            gemm_mfma<ushort><<<gemmGrid_C2, blk256, 0, stream>>>(ab, W2T_i, b2 + i * DMODEL, w2out,
                                                                  FFN_CHUNK, DMODEL, DFFN, DFFN, 0);
            add_ln_kernel<<<chunkRows, blk256, 0, stream>>>(x + (size_t)c * FFN_CHUNK * DMODEL,
                                                            xb + (size_t)c * FFN_CHUNK * DMODEL, w2out,
                                                            l2g + i * DMODEL, l2b + i * DMODEL);
        }
    }

    pool_kernel<<<dim3(BATCH), dim3(384), 0, stream>>>(x, mask, out);
}